// Round 3
// baseline (486.145 us; speedup 1.0000x reference)
//
#include <hip/hip_runtime.h>
#include <math.h>

typedef float f4 __attribute__((ext_vector_type(4)));
typedef float f2 __attribute__((ext_vector_type(2)));

#define L_LEN 2048
#define C_DIM 96
#define N_DIM 16
#define P_DIM 38
#define R_DIM 6
#define G_DIM 12
#define B_DIM 4
#define NCHUNK 32
#define CLEN 64
#define BGC (B_DIM * G_DIM * C_DIM) // 4608

// workspace layout (floats)
#define SZ_DELTA (B_DIM * G_DIM * C_DIM * L_LEN) // 9437184
#define SZ_BC (B_DIM * G_DIM * N_DIM * L_LEN)    // 1572864
#define SZ_U6 (B_DIM * 6 * C_DIM * L_LEN)        // 4718592
#define SZ_H (BGC * NCHUNK * N_DIM)              // 2359296

// ---------------- K1: cross-scan gather + projections ----------------
// thread = one (b,k,s,l). B/C now stored transposed: [bg][l][n] so the scan
// can read a channel's 16-state row as 4 contiguous f4 (wave-uniform).
__global__ __launch_bounds__(256) void k1_proj(
    const float* __restrict__ x, const float* __restrict__ xpw,
    const float* __restrict__ dtw, const float* __restrict__ dtb,
    float* __restrict__ delta, float* __restrict__ Bsw,
    float* __restrict__ Csw, float* __restrict__ u6)
{
    int blk = blockIdx.x;
    int ltile = blk & 7;
    int bks = blk >> 3;
    int s = bks % 3;
    int k = (bks / 3) & 3;
    int b = bks / 12;
    int g = k * 3 + s;
    int l = ltile * 256 + (int)threadIdx.x;
    int lf = (k < 2) ? l : (L_LEN - 1 - l);
    int s2 = lf & 1;
    int hh, ww;
    if ((k & 1) == 0) { hh = lf >> 6; ww = (lf >> 1) & 31; }
    else              { ww = lf >> 6; hh = (lf >> 1) & 31; }
    int pix = hh * 32 + ww;

    const float* xb = x + (size_t)b * 2 * C_DIM * 1024 + pix;
    const float* wp = xpw + (size_t)g * P_DIM * C_DIM;

    float acc[P_DIM];
#pragma unroll
    for (int p = 0; p < P_DIM; ++p) acc[p] = 0.f;

#pragma unroll 4
    for (int c = 0; c < C_DIM; ++c) {
        float x0 = xb[(size_t)c * 1024];
        float x1 = xb[(size_t)(C_DIM + c) * 1024];
        float v;
        if (s == 2)      v = s2 ? x1 : x0;
        else if (s2)     v = s ? x1 : x0;
        else             v = s ? (x1 - x0) : (x0 - x1);
        if (k < 2) u6[(((size_t)b * 6 + g) * C_DIM + c) * L_LEN + l] = v;
#pragma unroll
        for (int p = 0; p < P_DIM; ++p) acc[p] += v * wp[p * C_DIM + c];
    }

    size_t bg = (size_t)b * G_DIM + g;
    const float* wd = dtw + (size_t)g * C_DIM * R_DIM;
    const float* bias = dtb + g * C_DIM;
    for (int c = 0; c < C_DIM; ++c) {
        float dsum = bias[c];
#pragma unroll
        for (int r = 0; r < R_DIM; ++r) dsum += acc[r] * wd[c * R_DIM + r];
        float sp = (dsum > 20.f) ? dsum : log1pf(__expf(dsum));
        delta[(bg * C_DIM + c) * L_LEN + l] = sp;
    }
    size_t blbase = (bg * L_LEN + l) * N_DIM;
#pragma unroll
    for (int q = 0; q < 4; ++q) {
        f4 bv = { acc[6 + q * 4], acc[7 + q * 4], acc[8 + q * 4], acc[9 + q * 4] };
        f4 cv = { acc[22 + q * 4], acc[23 + q * 4], acc[24 + q * 4], acc[25 + q * 4] };
        *(f4*)(Bsw + blbase + q * 4) = bv;
        *(f4*)(Csw + blbase + q * 4) = cv;
    }
}

// ---------------- K2: chunk-parallel scan, 16 states per THREAD ----------------
// Pass A: per chunk with h0=0, compute h_end[16] and P[16]=prod(e).
__global__ __launch_bounds__(256) void k2_scanA(
    const float* __restrict__ delta, const float* __restrict__ Bsw,
    const float* __restrict__ u6, const float* __restrict__ A_logs,
    float* __restrict__ hend, float* __restrict__ prodE)
{
    int t = blockIdx.x * 256 + (int)threadIdx.x; // 147456
    int ch = t & (NCHUNK - 1);
    int bgc = t >> 5;
    int c = bgc % C_DIM;
    int bg = bgc / C_DIM;
    int g = bg % G_DIM;
    int b = bg / G_DIM;
    const bool rev = (g >= 6);
    int gu = rev ? (g - 6) : g;

    float a2[N_DIM];
    {
        const f4* Ap = (const f4*)(A_logs + ((size_t)g * C_DIM + c) * N_DIM);
        f4 Av[4] = { Ap[0], Ap[1], Ap[2], Ap[3] };
#pragma unroll
        for (int n = 0; n < N_DIM; ++n)
            a2[n] = -__expf(Av[n >> 2][n & 3]) * 1.44269504f;
    }

    const float* drow = delta + (size_t)bgc * L_LEN;
    const float* urow = u6 + (((size_t)b * 6 + gu) * C_DIM + c) * L_LEN;
    const float* Brow = Bsw + (size_t)bg * L_LEN * N_DIM;

    float h[N_DIM], P[N_DIM];
#pragma unroll
    for (int n = 0; n < N_DIM; ++n) { h[n] = 0.f; P[n] = 1.f; }

    const int LOFF = ch * CLEN;
    for (int l0 = LOFF; l0 < LOFF + CLEN; l0 += 4) {
        f4 d4 = *(const f4*)(drow + l0);
        f4 u4 = rev ? *(const f4*)(urow + (L_LEN - 4 - l0)) : *(const f4*)(urow + l0);
#pragma unroll
        for (int j = 0; j < 4; ++j) {
            float d = d4[j];
            float du = d * (rev ? u4[3 - j] : u4[j]);
            const f4* Bj = (const f4*)(Brow + (size_t)(l0 + j) * N_DIM);
            f4 Bv[4] = { Bj[0], Bj[1], Bj[2], Bj[3] };
#pragma unroll
            for (int n = 0; n < N_DIM; ++n) {
                float e = exp2f(d * a2[n]);
                P[n] *= e;
                h[n] = fmaf(h[n], e, du * Bv[n >> 2][n & 3]);
            }
        }
    }
    float* hp = hend + ((size_t)bgc * NCHUNK + ch) * N_DIM;
    float* pp = prodE + ((size_t)bgc * NCHUNK + ch) * N_DIM;
#pragma unroll
    for (int q = 0; q < 4; ++q) {
        f4 hv = { h[q * 4], h[q * 4 + 1], h[q * 4 + 2], h[q * 4 + 3] };
        f4 pv = { P[q * 4], P[q * 4 + 1], P[q * 4 + 2], P[q * 4 + 3] };
        *(f4*)(hp + q * 4) = hv;
        *(f4*)(pp + q * 4) = pv;
    }
}

// Pass B: compose chunk propagators. Overwrites prodE with hstart (in place).
__global__ __launch_bounds__(256) void k2_fix(
    const float* __restrict__ hend, float* prodE_hstart)
{
    int t = blockIdx.x * 256 + (int)threadIdx.x; // 73728
    int n = t & 15;
    int bgc = t >> 4;
    float h = 0.f;
    for (int ch = 0; ch < NCHUNK; ++ch) {
        size_t idx = ((size_t)bgc * NCHUNK + ch) * N_DIM + n;
        float Pv = prodE_hstart[idx];
        float he = hend[idx];
        prodE_hstart[idx] = h;
        h = fmaf(h, Pv, he);
    }
}

// Pass C: exact recurrence from hstart, writes y (+Ds*u folded).
__global__ __launch_bounds__(256) void k2_scanC(
    const float* __restrict__ delta, const float* __restrict__ Bsw,
    const float* __restrict__ Csw, const float* __restrict__ u6,
    const float* __restrict__ A_logs, const float* __restrict__ Ds,
    const float* __restrict__ hstart, float* __restrict__ yss)
{
    int t = blockIdx.x * 256 + (int)threadIdx.x;
    int ch = t & (NCHUNK - 1);
    int bgc = t >> 5;
    int c = bgc % C_DIM;
    int bg = bgc / C_DIM;
    int g = bg % G_DIM;
    int b = bg / G_DIM;
    const bool rev = (g >= 6);
    int gu = rev ? (g - 6) : g;

    float a2[N_DIM];
    {
        const f4* Ap = (const f4*)(A_logs + ((size_t)g * C_DIM + c) * N_DIM);
        f4 Av[4] = { Ap[0], Ap[1], Ap[2], Ap[3] };
#pragma unroll
        for (int n = 0; n < N_DIM; ++n)
            a2[n] = -__expf(Av[n >> 2][n & 3]) * 1.44269504f;
    }
    float dsc = Ds[g * C_DIM + c];

    const float* drow = delta + (size_t)bgc * L_LEN;
    const float* urow = u6 + (((size_t)b * 6 + gu) * C_DIM + c) * L_LEN;
    const float* Brow = Bsw + (size_t)bg * L_LEN * N_DIM;
    const float* Crow = Csw + (size_t)bg * L_LEN * N_DIM;
    float* yrow = yss + (size_t)bgc * L_LEN;

    float h[N_DIM];
    {
        const f4* Hp = (const f4*)(hstart + ((size_t)bgc * NCHUNK + ch) * N_DIM);
        f4 Hv[4] = { Hp[0], Hp[1], Hp[2], Hp[3] };
#pragma unroll
        for (int n = 0; n < N_DIM; ++n) h[n] = Hv[n >> 2][n & 3];
    }

    const int LOFF = ch * CLEN;
    for (int l0 = LOFF; l0 < LOFF + CLEN; l0 += 4) {
        f4 d4 = *(const f4*)(drow + l0);
        f4 u4 = rev ? *(const f4*)(urow + (L_LEN - 4 - l0)) : *(const f4*)(urow + l0);
        f4 y4;
#pragma unroll
        for (int j = 0; j < 4; ++j) {
            float d = d4[j];
            float uu = rev ? u4[3 - j] : u4[j];
            float du = d * uu;
            const f4* Bj = (const f4*)(Brow + (size_t)(l0 + j) * N_DIM);
            const f4* Cj = (const f4*)(Crow + (size_t)(l0 + j) * N_DIM);
            f4 Bv[4] = { Bj[0], Bj[1], Bj[2], Bj[3] };
            f4 Cv[4] = { Cj[0], Cj[1], Cj[2], Cj[3] };
            float y = dsc * uu;
#pragma unroll
            for (int n = 0; n < N_DIM; ++n) {
                float e = exp2f(d * a2[n]);
                h[n] = fmaf(h[n], e, du * Bv[n >> 2][n & 3]);
                y = fmaf(h[n], Cv[n >> 2][n & 3], y);
            }
            y4[j] = y;
        }
        *(f4*)(yrow + l0) = y4;
    }
}

// ---------------- K3: fold (un-scan) + LayerNorm, fused ----------------
__global__ __launch_bounds__(256) void k3_out(
    const float* __restrict__ yss, const float* __restrict__ nw,
    const float* __restrict__ nb, float* __restrict__ out)
{
    __shared__ float tA[32][97];
    __shared__ float tB[32][97];
    __shared__ float ps[4][8][32];
    __shared__ float stat[4][32];

    int blk = blockIdx.x;
    int h = blk & 31;
    int bs = blk >> 5;
    int so = bs & 1;
    int b = bs >> 1;
    int w = threadIdx.x & 31;
    int cg = threadIdx.x >> 5;
    int l0 = (h * 32 + w) * 2;
    int l1 = (w * 32 + h) * 2;

    auto Yp = [&](int g, int c) {
        return yss + (((size_t)b * 12 + g) * C_DIM + c) * L_LEN;
    };

    float sA = 0, qA = 0, sB = 0, qB = 0;
    for (int j = 0; j < 12; ++j) {
        int c = cg * 12 + j;
        f2 f0 = *(const f2*)(Yp(so, c) + l0);
        f2 r0 = *(const f2*)(Yp(6 + so, c) + (2046 - l0));
        f2 f1 = *(const f2*)(Yp(3 + so, c) + l1);
        f2 r1 = *(const f2*)(Yp(9 + so, c) + (2046 - l1));
        float ys0_a = f0.x + r0.y;
        float ys0_b = f0.y + r0.x;
        float ys1_a = f1.x + r1.y;
        float ys1_b = f1.y + r1.x;
        float yv = ys0_b + ys1_b;
        float dv = ys0_a + ys1_a;
        tA[w][c] = yv; tB[w][c] = dv;
        sA += yv; qA += yv * yv; sB += dv; qB += dv * dv;
    }
    ps[0][cg][w] = sA; ps[1][cg][w] = qA; ps[2][cg][w] = sB; ps[3][cg][w] = qB;
    __syncthreads();
    if (threadIdx.x < 32) {
        int ww = threadIdx.x;
        float t0 = 0, t1 = 0, t2 = 0, t3 = 0;
#pragma unroll
        for (int q = 0; q < 8; ++q) {
            t0 += ps[0][q][ww]; t1 += ps[1][q][ww];
            t2 += ps[2][q][ww]; t3 += ps[3][q][ww];
        }
        float muA = t0 * (1.f / 96.f), eqA = t1 * (1.f / 96.f);
        float muB = t2 * (1.f / 96.f), eqB = t3 * (1.f / 96.f);
        stat[0][ww] = muA; stat[1][ww] = rsqrtf(eqA - muA * muA + 1e-5f);
        stat[2][ww] = muB; stat[3][ww] = rsqrtf(eqB - muB * muB + 1e-5f);
    }
    __syncthreads();
    size_t obase = (size_t)blk * 3072;
    for (int e = threadIdx.x; e < 3072; e += 256) {
        int ww = e / 96, c = e % 96;
        float wc = nw[c], bc = nb[c];
        out[obase + e] = (tA[ww][c] - stat[0][ww]) * stat[1][ww] * wc + bc;
        out[2 * 786432 + obase + e] = (tB[ww][c] - stat[2][ww]) * stat[3][ww] * wc + bc;
    }
    __syncthreads();

    float sC = 0, qC = 0;
    for (int j = 0; j < 12; ++j) {
        int c = cg * 12 + j;
        f2 f0 = *(const f2*)(Yp(2, c) + l0);
        f2 r0 = *(const f2*)(Yp(8, c) + (2046 - l0));
        f2 f1 = *(const f2*)(Yp(5, c) + l1);
        f2 r1 = *(const f2*)(Yp(11, c) + (2046 - l1));
        float v;
        if (so == 0) v = (f0.x + r0.y) + (f1.x + r1.y);
        else         v = (f0.y + r0.x) + (f1.y + r1.x);
        tA[w][c] = v; sC += v; qC += v * v;
    }
    ps[0][cg][w] = sC; ps[1][cg][w] = qC;
    __syncthreads();
    if (threadIdx.x < 32) {
        int ww = threadIdx.x;
        float t0 = 0, t1 = 0;
#pragma unroll
        for (int q = 0; q < 8; ++q) { t0 += ps[0][q][ww]; t1 += ps[1][q][ww]; }
        float mu = t0 * (1.f / 96.f), eq = t1 * (1.f / 96.f);
        stat[0][ww] = mu; stat[1][ww] = rsqrtf(eq - mu * mu + 1e-5f);
    }
    __syncthreads();
    for (int e = threadIdx.x; e < 3072; e += 256) {
        int ww = e / 96, c = e % 96;
        out[786432 + obase + e] = (tA[ww][c] - stat[0][ww]) * stat[1][ww] * nw[c] + nb[c];
    }
}

extern "C" void kernel_launch(void* const* d_in, const int* in_sizes, int n_in,
                              void* d_out, int out_size, void* d_ws, size_t ws_size,
                              hipStream_t stream)
{
    const float* x = (const float*)d_in[0];
    const float* xpw = (const float*)d_in[1];
    const float* dtw = (const float*)d_in[2];
    const float* dtb = (const float*)d_in[3];
    const float* A_logs = (const float*)d_in[4];
    const float* Ds = (const float*)d_in[5];
    const float* nw = (const float*)d_in[6];
    const float* nb = (const float*)d_in[7];
    float* out = (float*)d_out;

    float* ws = (float*)d_ws;
    float* delta = ws;                 // SZ_DELTA
    float* Bsw = delta + SZ_DELTA;     // SZ_BC
    float* Csw = Bsw + SZ_BC;          // SZ_BC
    float* u6 = Csw + SZ_BC;           // SZ_U6
    float* yss = u6 + SZ_U6;           // SZ_DELTA
    float* hend = yss + SZ_DELTA;      // SZ_H
    float* prodE = hend + SZ_H;        // SZ_H (then reused as hstart)

    k1_proj<<<dim3(48 * 8), dim3(256), 0, stream>>>(x, xpw, dtw, dtb, delta, Bsw, Csw, u6);
    k2_scanA<<<dim3(576), dim3(256), 0, stream>>>(delta, Bsw, u6, A_logs, hend, prodE);
    k2_fix<<<dim3(288), dim3(256), 0, stream>>>(hend, prodE);
    k2_scanC<<<dim3(576), dim3(256), 0, stream>>>(delta, Bsw, Csw, u6, A_logs, Ds, prodE, yss);
    k3_out<<<dim3(256), dim3(256), 0, stream>>>(yss, nw, nb, out);
}

// Round 4
// 323.589 us; speedup vs baseline: 1.5024x; 1.5024x over previous
//
#include <hip/hip_runtime.h>
#include <math.h>

typedef float f4 __attribute__((ext_vector_type(4)));
typedef float f2 __attribute__((ext_vector_type(2)));

#define L_LEN 2048
#define C_DIM 96
#define N_DIM 16
#define P_DIM 38
#define R_DIM 6
#define G_DIM 12
#define B_DIM 4
#define NCHUNK 32
#define CLEN 64
#define BGC (B_DIM * G_DIM * C_DIM) // 4608

// workspace layout (floats)
#define SZ_DELTA (B_DIM * G_DIM * C_DIM * L_LEN) // 9437184
#define SZ_BC (B_DIM * G_DIM * N_DIM * L_LEN)    // 1572864
#define SZ_U6 (B_DIM * 6 * C_DIM * L_LEN)        // 4718592
#define SZ_H (BGC * NCHUNK * N_DIM)              // 2359296

// ---------------- K1: cross-scan gather + projections ----------------
__global__ __launch_bounds__(256) void k1_proj(
    const float* __restrict__ x, const float* __restrict__ xpw,
    const float* __restrict__ dtw, const float* __restrict__ dtb,
    float* __restrict__ delta, float* __restrict__ Bsw,
    float* __restrict__ Csw, float* __restrict__ u6)
{
    int blk = blockIdx.x;
    int ltile = blk & 7;
    int bks = blk >> 3;
    int s = bks % 3;
    int k = (bks / 3) & 3;
    int b = bks / 12;
    int g = k * 3 + s;
    int l = ltile * 256 + (int)threadIdx.x;
    int lf = (k < 2) ? l : (L_LEN - 1 - l);
    int s2 = lf & 1;
    int hh, ww;
    if ((k & 1) == 0) { hh = lf >> 6; ww = (lf >> 1) & 31; }
    else              { ww = lf >> 6; hh = (lf >> 1) & 31; }
    int pix = hh * 32 + ww;

    const float* xb = x + (size_t)b * 2 * C_DIM * 1024 + pix;
    const float* wp = xpw + (size_t)g * P_DIM * C_DIM;

    float acc[P_DIM];
#pragma unroll
    for (int p = 0; p < P_DIM; ++p) acc[p] = 0.f;

#pragma unroll 4
    for (int c = 0; c < C_DIM; ++c) {
        float x0 = xb[(size_t)c * 1024];
        float x1 = xb[(size_t)(C_DIM + c) * 1024];
        float v;
        if (s == 2)      v = s2 ? x1 : x0;
        else if (s2)     v = s ? x1 : x0;
        else             v = s ? (x1 - x0) : (x0 - x1);
        if (k < 2) u6[(((size_t)b * 6 + g) * C_DIM + c) * L_LEN + l] = v;
#pragma unroll
        for (int p = 0; p < P_DIM; ++p) acc[p] += v * wp[p * C_DIM + c];
    }

    size_t bg = (size_t)b * G_DIM + g;
    const float* wd = dtw + (size_t)g * C_DIM * R_DIM;
    const float* bias = dtb + g * C_DIM;
    for (int c = 0; c < C_DIM; ++c) {
        float dsum = bias[c];
#pragma unroll
        for (int r = 0; r < R_DIM; ++r) dsum += acc[r] * wd[c * R_DIM + r];
        float sp = (dsum > 20.f) ? dsum : log1pf(__expf(dsum));
        delta[(bg * C_DIM + c) * L_LEN + l] = sp;
    }
    size_t blbase = (bg * L_LEN + l) * N_DIM;
#pragma unroll
    for (int q = 0; q < 4; ++q) {
        f4 bv = { acc[6 + q * 4], acc[7 + q * 4], acc[8 + q * 4], acc[9 + q * 4] };
        f4 cv = { acc[22 + q * 4], acc[23 + q * 4], acc[24 + q * 4], acc[25 + q * 4] };
        *(f4*)(Bsw + blbase + q * 4) = bv;
        *(f4*)(Csw + blbase + q * 4) = cv;
    }
}

// ---------------- K2: chunk-parallel scan, B/C staged in LDS ----------------
// block = 192 threads = one bg x 2 chunks x 96 channels; B/C rows for the
// 128-l window staged cooperatively, read back as LDS broadcast.

// Pass A: per chunk with h0=0, compute h_end[16] and P[16]=prod(e).
__global__ __launch_bounds__(192) void k2_scanA(
    const float* __restrict__ delta, const float* __restrict__ Bsw,
    const float* __restrict__ u6, const float* __restrict__ A_logs,
    float* __restrict__ hend, float* __restrict__ prodE)
{
    __shared__ f4 Bsh[512]; // 128 l x 16 n
    int blk = blockIdx.x;
    int chgrp = blk & 15;
    int bg = blk >> 4;
    int g = bg % G_DIM;
    int b = bg / G_DIM;
    int tid = (int)threadIdx.x;

    const f4* Bg = (const f4*)(Bsw + ((size_t)bg * L_LEN + chgrp * 128) * N_DIM);
    for (int i = tid; i < 512; i += 192) Bsh[i] = Bg[i];
    __syncthreads();

    int chl = tid / 96;
    int c = tid % 96;
    int ch = chgrp * 2 + chl;
    int bgc = bg * C_DIM + c;
    const bool rev = (g >= 6);
    int gu = rev ? (g - 6) : g;

    float a2[N_DIM];
    {
        const f4* Ap = (const f4*)(A_logs + ((size_t)g * C_DIM + c) * N_DIM);
        f4 Av[4] = { Ap[0], Ap[1], Ap[2], Ap[3] };
#pragma unroll
        for (int n = 0; n < N_DIM; ++n)
            a2[n] = -__expf(Av[n >> 2][n & 3]) * 1.44269504f;
    }

    const float* drow = delta + (size_t)bgc * L_LEN;
    const float* urow = u6 + (((size_t)b * 6 + gu) * C_DIM + c) * L_LEN;

    float h[N_DIM], P[N_DIM];
#pragma unroll
    for (int n = 0; n < N_DIM; ++n) { h[n] = 0.f; P[n] = 1.f; }

    const int LOFF = ch * CLEN;
#pragma unroll 2
    for (int l4 = 0; l4 < CLEN; l4 += 4) {
        int lg = LOFF + l4;
        f4 d4 = *(const f4*)(drow + lg);
        f4 u4 = rev ? *(const f4*)(urow + (L_LEN - 4 - lg)) : *(const f4*)(urow + lg);
#pragma unroll
        for (int j = 0; j < 4; ++j) {
            float d = d4[j];
            float du = d * (rev ? u4[3 - j] : u4[j]);
            const f4* Bl = Bsh + (size_t)(chl * CLEN + l4 + j) * 4;
            f4 Bv[4] = { Bl[0], Bl[1], Bl[2], Bl[3] };
#pragma unroll
            for (int n = 0; n < N_DIM; ++n) {
                float e = exp2f(d * a2[n]);
                P[n] *= e;
                h[n] = fmaf(h[n], e, du * Bv[n >> 2][n & 3]);
            }
        }
    }
    float* hp = hend + ((size_t)bgc * NCHUNK + ch) * N_DIM;
    float* pp = prodE + ((size_t)bgc * NCHUNK + ch) * N_DIM;
#pragma unroll
    for (int q = 0; q < 4; ++q) {
        f4 hv = { h[q * 4], h[q * 4 + 1], h[q * 4 + 2], h[q * 4 + 3] };
        f4 pv = { P[q * 4], P[q * 4 + 1], P[q * 4 + 2], P[q * 4 + 3] };
        *(f4*)(hp + q * 4) = hv;
        *(f4*)(pp + q * 4) = pv;
    }
}

// Pass B: compose chunk propagators. Overwrites prodE with hstart (in place).
__global__ __launch_bounds__(256) void k2_fix(
    const float* __restrict__ hend, float* prodE_hstart)
{
    int t = blockIdx.x * 256 + (int)threadIdx.x; // 73728
    int n = t & 15;
    int bgc = t >> 4;
    float h = 0.f;
    for (int ch = 0; ch < NCHUNK; ++ch) {
        size_t idx = ((size_t)bgc * NCHUNK + ch) * N_DIM + n;
        float Pv = prodE_hstart[idx];
        float he = hend[idx];
        prodE_hstart[idx] = h;
        h = fmaf(h, Pv, he);
    }
}

// Pass C: exact recurrence from hstart, writes y (+Ds*u folded).
__global__ __launch_bounds__(192) void k2_scanC(
    const float* __restrict__ delta, const float* __restrict__ Bsw,
    const float* __restrict__ Csw, const float* __restrict__ u6,
    const float* __restrict__ A_logs, const float* __restrict__ Ds,
    const float* __restrict__ hstart, float* __restrict__ yss)
{
    __shared__ f4 Bsh[512];
    __shared__ f4 Csh[512];
    int blk = blockIdx.x;
    int chgrp = blk & 15;
    int bg = blk >> 4;
    int g = bg % G_DIM;
    int b = bg / G_DIM;
    int tid = (int)threadIdx.x;

    const f4* Bg = (const f4*)(Bsw + ((size_t)bg * L_LEN + chgrp * 128) * N_DIM);
    const f4* Cg = (const f4*)(Csw + ((size_t)bg * L_LEN + chgrp * 128) * N_DIM);
    for (int i = tid; i < 512; i += 192) { Bsh[i] = Bg[i]; Csh[i] = Cg[i]; }
    __syncthreads();

    int chl = tid / 96;
    int c = tid % 96;
    int ch = chgrp * 2 + chl;
    int bgc = bg * C_DIM + c;
    const bool rev = (g >= 6);
    int gu = rev ? (g - 6) : g;

    float a2[N_DIM];
    {
        const f4* Ap = (const f4*)(A_logs + ((size_t)g * C_DIM + c) * N_DIM);
        f4 Av[4] = { Ap[0], Ap[1], Ap[2], Ap[3] };
#pragma unroll
        for (int n = 0; n < N_DIM; ++n)
            a2[n] = -__expf(Av[n >> 2][n & 3]) * 1.44269504f;
    }
    float dsc = Ds[g * C_DIM + c];

    const float* drow = delta + (size_t)bgc * L_LEN;
    const float* urow = u6 + (((size_t)b * 6 + gu) * C_DIM + c) * L_LEN;
    float* yrow = yss + (size_t)bgc * L_LEN;

    float h[N_DIM];
    {
        const f4* Hp = (const f4*)(hstart + ((size_t)bgc * NCHUNK + ch) * N_DIM);
        f4 Hv[4] = { Hp[0], Hp[1], Hp[2], Hp[3] };
#pragma unroll
        for (int n = 0; n < N_DIM; ++n) h[n] = Hv[n >> 2][n & 3];
    }

    const int LOFF = ch * CLEN;
#pragma unroll 2
    for (int l4 = 0; l4 < CLEN; l4 += 4) {
        int lg = LOFF + l4;
        f4 d4 = *(const f4*)(drow + lg);
        f4 u4 = rev ? *(const f4*)(urow + (L_LEN - 4 - lg)) : *(const f4*)(urow + lg);
        f4 y4;
#pragma unroll
        for (int j = 0; j < 4; ++j) {
            float d = d4[j];
            float uu = rev ? u4[3 - j] : u4[j];
            float du = d * uu;
            const f4* Bl = Bsh + (size_t)(chl * CLEN + l4 + j) * 4;
            const f4* Cl = Csh + (size_t)(chl * CLEN + l4 + j) * 4;
            f4 Bv[4] = { Bl[0], Bl[1], Bl[2], Bl[3] };
            f4 Cv[4] = { Cl[0], Cl[1], Cl[2], Cl[3] };
            float y = dsc * uu;
#pragma unroll
            for (int n = 0; n < N_DIM; ++n) {
                float e = exp2f(d * a2[n]);
                h[n] = fmaf(h[n], e, du * Bv[n >> 2][n & 3]);
                y = fmaf(h[n], Cv[n >> 2][n & 3], y);
            }
            y4[j] = y;
        }
        *(f4*)(yrow + lg) = y4;
    }
}

// ---------------- K3: fold (un-scan) + LayerNorm, fused ----------------
__global__ __launch_bounds__(256) void k3_out(
    const float* __restrict__ yss, const float* __restrict__ nw,
    const float* __restrict__ nb, float* __restrict__ out)
{
    __shared__ float tA[32][97];
    __shared__ float tB[32][97];
    __shared__ float ps[4][8][32];
    __shared__ float stat[4][32];

    int blk = blockIdx.x;
    int h = blk & 31;
    int bs = blk >> 5;
    int so = bs & 1;
    int b = bs >> 1;
    int w = threadIdx.x & 31;
    int cg = threadIdx.x >> 5;
    int l0 = (h * 32 + w) * 2;
    int l1 = (w * 32 + h) * 2;

    auto Yp = [&](int g, int c) {
        return yss + (((size_t)b * 12 + g) * C_DIM + c) * L_LEN;
    };

    float sA = 0, qA = 0, sB = 0, qB = 0;
    for (int j = 0; j < 12; ++j) {
        int c = cg * 12 + j;
        f2 f0 = *(const f2*)(Yp(so, c) + l0);
        f2 r0 = *(const f2*)(Yp(6 + so, c) + (2046 - l0));
        f2 f1 = *(const f2*)(Yp(3 + so, c) + l1);
        f2 r1 = *(const f2*)(Yp(9 + so, c) + (2046 - l1));
        float ys0_a = f0.x + r0.y;
        float ys0_b = f0.y + r0.x;
        float ys1_a = f1.x + r1.y;
        float ys1_b = f1.y + r1.x;
        float yv = ys0_b + ys1_b;
        float dv = ys0_a + ys1_a;
        tA[w][c] = yv; tB[w][c] = dv;
        sA += yv; qA += yv * yv; sB += dv; qB += dv * dv;
    }
    ps[0][cg][w] = sA; ps[1][cg][w] = qA; ps[2][cg][w] = sB; ps[3][cg][w] = qB;
    __syncthreads();
    if (threadIdx.x < 32) {
        int ww = threadIdx.x;
        float t0 = 0, t1 = 0, t2 = 0, t3 = 0;
#pragma unroll
        for (int q = 0; q < 8; ++q) {
            t0 += ps[0][q][ww]; t1 += ps[1][q][ww];
            t2 += ps[2][q][ww]; t3 += ps[3][q][ww];
        }
        float muA = t0 * (1.f / 96.f), eqA = t1 * (1.f / 96.f);
        float muB = t2 * (1.f / 96.f), eqB = t3 * (1.f / 96.f);
        stat[0][ww] = muA; stat[1][ww] = rsqrtf(eqA - muA * muA + 1e-5f);
        stat[2][ww] = muB; stat[3][ww] = rsqrtf(eqB - muB * muB + 1e-5f);
    }
    __syncthreads();
    size_t obase = (size_t)blk * 3072;
    for (int e = threadIdx.x; e < 3072; e += 256) {
        int ww = e / 96, c = e % 96;
        float wc = nw[c], bc = nb[c];
        out[obase + e] = (tA[ww][c] - stat[0][ww]) * stat[1][ww] * wc + bc;
        out[2 * 786432 + obase + e] = (tB[ww][c] - stat[2][ww]) * stat[3][ww] * wc + bc;
    }
    __syncthreads();

    float sC = 0, qC = 0;
    for (int j = 0; j < 12; ++j) {
        int c = cg * 12 + j;
        f2 f0 = *(const f2*)(Yp(2, c) + l0);
        f2 r0 = *(const f2*)(Yp(8, c) + (2046 - l0));
        f2 f1 = *(const f2*)(Yp(5, c) + l1);
        f2 r1 = *(const f2*)(Yp(11, c) + (2046 - l1));
        float v;
        if (so == 0) v = (f0.x + r0.y) + (f1.x + r1.y);
        else         v = (f0.y + r0.x) + (f1.y + r1.x);
        tA[w][c] = v; sC += v; qC += v * v;
    }
    ps[0][cg][w] = sC; ps[1][cg][w] = qC;
    __syncthreads();
    if (threadIdx.x < 32) {
        int ww = threadIdx.x;
        float t0 = 0, t1 = 0;
#pragma unroll
        for (int q = 0; q < 8; ++q) { t0 += ps[0][q][ww]; t1 += ps[1][q][ww]; }
        float mu = t0 * (1.f / 96.f), eq = t1 * (1.f / 96.f);
        stat[0][ww] = mu; stat[1][ww] = rsqrtf(eq - mu * mu + 1e-5f);
    }
    __syncthreads();
    for (int e = threadIdx.x; e < 3072; e += 256) {
        int ww = e / 96, c = e % 96;
        out[786432 + obase + e] = (tA[ww][c] - stat[0][ww]) * stat[1][ww] * nw[c] + nb[c];
    }
}

extern "C" void kernel_launch(void* const* d_in, const int* in_sizes, int n_in,
                              void* d_out, int out_size, void* d_ws, size_t ws_size,
                              hipStream_t stream)
{
    const float* x = (const float*)d_in[0];
    const float* xpw = (const float*)d_in[1];
    const float* dtw = (const float*)d_in[2];
    const float* dtb = (const float*)d_in[3];
    const float* A_logs = (const float*)d_in[4];
    const float* Ds = (const float*)d_in[5];
    const float* nw = (const float*)d_in[6];
    const float* nb = (const float*)d_in[7];
    float* out = (float*)d_out;

    float* ws = (float*)d_ws;
    float* delta = ws;                 // SZ_DELTA
    float* Bsw = delta + SZ_DELTA;     // SZ_BC
    float* Csw = Bsw + SZ_BC;          // SZ_BC
    float* u6 = Csw + SZ_BC;           // SZ_U6
    float* yss = u6 + SZ_U6;           // SZ_DELTA
    float* hend = yss + SZ_DELTA;      // SZ_H
    float* prodE = hend + SZ_H;        // SZ_H (then reused as hstart)

    k1_proj<<<dim3(48 * 8), dim3(256), 0, stream>>>(x, xpw, dtw, dtb, delta, Bsw, Csw, u6);
    k2_scanA<<<dim3(48 * 16), dim3(192), 0, stream>>>(delta, Bsw, u6, A_logs, hend, prodE);
    k2_fix<<<dim3(288), dim3(256), 0, stream>>>(hend, prodE);
    k2_scanC<<<dim3(48 * 16), dim3(192), 0, stream>>>(delta, Bsw, Csw, u6, A_logs, Ds, prodE, yss);
    k3_out<<<dim3(256), dim3(256), 0, stream>>>(yss, nw, nb, out);
}

// Round 5
// 304.299 us; speedup vs baseline: 1.5976x; 1.0634x over previous
//
#include <hip/hip_runtime.h>
#include <math.h>

typedef float f4 __attribute__((ext_vector_type(4)));
typedef float f2 __attribute__((ext_vector_type(2)));

#define L_LEN 2048
#define C_DIM 96
#define N_DIM 16
#define P_DIM 38
#define R_DIM 6
#define G_DIM 12
#define B_DIM 4
#define NCHUNK 32
#define CLEN 64
#define BGC (B_DIM * G_DIM * C_DIM) // 4608

// workspace layout (floats)
#define SZ_DELTA (B_DIM * G_DIM * C_DIM * L_LEN) // 9437184
#define SZ_BC (B_DIM * G_DIM * N_DIM * L_LEN)    // 1572864
#define SZ_U6 (B_DIM * 6 * C_DIM * L_LEN)        // 4718592
#define SZ_H (BGC * NCHUNK * N_DIM)              // 2359296
#define SZ_X (B_DIM * 2 * C_DIM * 1024)          // 786432

// ---------------- K0: transpose x (H<->W) for odd-k coalescing ----------------
__global__ __launch_bounds__(256) void k0_xT(
    const float* __restrict__ x, float* __restrict__ xT)
{
    __shared__ float t[32][33];
    int img = blockIdx.x; // (b,s,c) image, 768 total
    const float* src = x + (size_t)img * 1024;
    float* dst = xT + (size_t)img * 1024;
    int tx = threadIdx.x & 31, ty = threadIdx.x >> 5;
#pragma unroll
    for (int r = 0; r < 32; r += 8) t[ty + r][tx] = src[(ty + r) * 32 + tx];
    __syncthreads();
#pragma unroll
    for (int r = 0; r < 32; r += 8) dst[(ty + r) * 32 + tx] = t[tx][ty + r];
}

// ---------------- K1: cross-scan gather + projections (LDS-tiled GEMM) ----------------
// block = (b, g, 64-l tile). Stage V[c][ll] in LDS, then thread=(ll, pgroup)
// accumulates ~10 rows of the 38x96 projection in registers.
__global__ __launch_bounds__(256) void k1_proj(
    const float* __restrict__ x, const float* __restrict__ xT,
    const float* __restrict__ xpw, const float* __restrict__ dtw,
    const float* __restrict__ dtb, float* __restrict__ delta,
    float* __restrict__ Bsw, float* __restrict__ Csw, float* __restrict__ u6)
{
    __shared__ float Vsh[C_DIM * 64];
    __shared__ float As[R_DIM * 64];

    int blk = blockIdx.x;          // bg*32 + ltile
    int ltile = blk & 31;
    int bg = blk >> 5;             // 0..47
    int g = bg % G_DIM, b = bg / G_DIM;
    int k = g / 3, s = g % 3;
    int l0 = ltile * 64;
    int tid = (int)threadIdx.x;

    const float* xb = ((k & 1) ? xT : x) + (size_t)b * 2 * C_DIM * 1024;

    // ---- stage V (and u6 for g<6) ----
    for (int idx = tid; idx < C_DIM * 64; idx += 256) {
        int c = idx >> 6, ll = idx & 63;
        int l = l0 + ll;
        int lf = (k < 2) ? l : (2047 - l);
        int s2 = lf & 1, pp = lf >> 1;
        float x0 = xb[(size_t)c * 1024 + pp];
        float x1 = xb[(size_t)(C_DIM + c) * 1024 + pp];
        float v;
        if (s == 2)  v = s2 ? x1 : x0;
        else if (s2) v = s ? x1 : x0;
        else         v = s ? (x1 - x0) : (x0 - x1);
        Vsh[idx] = v;
        if (g < 6) u6[(((size_t)b * 6 + g) * C_DIM + c) * L_LEN + l] = v;
    }
    __syncthreads();

    // ---- register GEMM: acc[p] = sum_c w[p][c] * V[c][ll] ----
    int ll = tid & 63, pg = tid >> 6;
    int P0 = pg * 10;
    int PN = (pg == 3) ? 8 : 10;
    const float* wp = xpw + (size_t)g * P_DIM * C_DIM + (size_t)P0 * C_DIM;

    float acc[10];
#pragma unroll
    for (int p = 0; p < 10; ++p) acc[p] = 0.f;

    for (int cb = 0; cb < C_DIM; cb += 16) {
        float vc[16];
#pragma unroll
        for (int i = 0; i < 16; ++i) vc[i] = Vsh[(cb + i) * 64 + ll];
#pragma unroll
        for (int p = 0; p < 10; ++p) {
            if (p < PN) {
#pragma unroll
                for (int i = 0; i < 16; ++i)
                    acc[p] = fmaf(wp[p * C_DIM + cb + i], vc[i], acc[p]);
            }
        }
    }

    // ---- write B/C from regs; stage dts rows to LDS ----
    size_t lbase = ((size_t)bg * L_LEN + l0 + ll) * N_DIM;
#pragma unroll
    for (int p = 0; p < 10; ++p) {
        int pa = P0 + p;
        if (p < PN && pa >= 6) {
            if (pa < 22) Bsw[lbase + (pa - 6)] = acc[p];
            else         Csw[lbase + (pa - 22)] = acc[p];
        }
    }
    if (pg == 0) {
#pragma unroll
        for (int p = 0; p < 6; ++p) As[p * 64 + ll] = acc[p];
    }
    __syncthreads();

    // ---- delta: dt-proj + bias + softplus, coalesced over l ----
    const float* wd = dtw + (size_t)g * C_DIM * R_DIM;
    const float* bias = dtb + g * C_DIM;
    for (int e = tid; e < C_DIM * 64; e += 256) {
        int c = e >> 6, l2 = e & 63;
        float dsum = bias[c];
#pragma unroll
        for (int r = 0; r < R_DIM; ++r) dsum = fmaf(As[r * 64 + l2], wd[c * R_DIM + r], dsum);
        float sp = (dsum > 20.f) ? dsum : log1pf(__expf(dsum));
        delta[((size_t)bg * C_DIM + c) * L_LEN + l0 + l2] = sp;
    }
}

// ---------------- K2: chunk-parallel scan, B/C staged in LDS ----------------
// Pass A: per chunk with h0=0, compute h_end[16] and P[16]=prod(e).
__global__ __launch_bounds__(192) void k2_scanA(
    const float* __restrict__ delta, const float* __restrict__ Bsw,
    const float* __restrict__ u6, const float* __restrict__ A_logs,
    float* __restrict__ hend, float* __restrict__ prodE)
{
    __shared__ f4 Bsh[512]; // 128 l x 16 n
    int blk = blockIdx.x;
    int chgrp = blk & 15;
    int bg = blk >> 4;
    int g = bg % G_DIM;
    int b = bg / G_DIM;
    int tid = (int)threadIdx.x;

    const f4* Bg = (const f4*)(Bsw + ((size_t)bg * L_LEN + chgrp * 128) * N_DIM);
    for (int i = tid; i < 512; i += 192) Bsh[i] = Bg[i];
    __syncthreads();

    int chl = tid / 96;
    int c = tid % 96;
    int ch = chgrp * 2 + chl;
    int bgc = bg * C_DIM + c;
    const bool rev = (g >= 6);
    int gu = rev ? (g - 6) : g;

    float a2[N_DIM];
    {
        const f4* Ap = (const f4*)(A_logs + ((size_t)g * C_DIM + c) * N_DIM);
        f4 Av[4] = { Ap[0], Ap[1], Ap[2], Ap[3] };
#pragma unroll
        for (int n = 0; n < N_DIM; ++n)
            a2[n] = -__expf(Av[n >> 2][n & 3]) * 1.44269504f;
    }

    const float* drow = delta + (size_t)bgc * L_LEN;
    const float* urow = u6 + (((size_t)b * 6 + gu) * C_DIM + c) * L_LEN;

    float h[N_DIM], P[N_DIM];
#pragma unroll
    for (int n = 0; n < N_DIM; ++n) { h[n] = 0.f; P[n] = 1.f; }

    const int LOFF = ch * CLEN;
#pragma unroll 2
    for (int l4 = 0; l4 < CLEN; l4 += 4) {
        int lg = LOFF + l4;
        f4 d4 = *(const f4*)(drow + lg);
        f4 u4 = rev ? *(const f4*)(urow + (L_LEN - 4 - lg)) : *(const f4*)(urow + lg);
#pragma unroll
        for (int j = 0; j < 4; ++j) {
            float d = d4[j];
            float du = d * (rev ? u4[3 - j] : u4[j]);
            const f4* Bl = Bsh + (size_t)(chl * CLEN + l4 + j) * 4;
            f4 Bv[4] = { Bl[0], Bl[1], Bl[2], Bl[3] };
#pragma unroll
            for (int n = 0; n < N_DIM; ++n) {
                float e = exp2f(d * a2[n]);
                P[n] *= e;
                h[n] = fmaf(h[n], e, du * Bv[n >> 2][n & 3]);
            }
        }
    }
    float* hp = hend + ((size_t)bgc * NCHUNK + ch) * N_DIM;
    float* pp = prodE + ((size_t)bgc * NCHUNK + ch) * N_DIM;
#pragma unroll
    for (int q = 0; q < 4; ++q) {
        f4 hv = { h[q * 4], h[q * 4 + 1], h[q * 4 + 2], h[q * 4 + 3] };
        f4 pv = { P[q * 4], P[q * 4 + 1], P[q * 4 + 2], P[q * 4 + 3] };
        *(f4*)(hp + q * 4) = hv;
        *(f4*)(pp + q * 4) = pv;
    }
}

// Pass B: compose chunk propagators. Overwrites prodE with hstart (in place).
__global__ __launch_bounds__(256) void k2_fix(
    const float* __restrict__ hend, float* prodE_hstart)
{
    int t = blockIdx.x * 256 + (int)threadIdx.x; // 73728
    int n = t & 15;
    int bgc = t >> 4;
    float h = 0.f;
    for (int ch = 0; ch < NCHUNK; ++ch) {
        size_t idx = ((size_t)bgc * NCHUNK + ch) * N_DIM + n;
        float Pv = prodE_hstart[idx];
        float he = hend[idx];
        prodE_hstart[idx] = h;
        h = fmaf(h, Pv, he);
    }
}

// Pass C: exact recurrence from hstart, writes y (+Ds*u folded).
__global__ __launch_bounds__(192) void k2_scanC(
    const float* __restrict__ delta, const float* __restrict__ Bsw,
    const float* __restrict__ Csw, const float* __restrict__ u6,
    const float* __restrict__ A_logs, const float* __restrict__ Ds,
    const float* __restrict__ hstart, float* __restrict__ yss)
{
    __shared__ f4 Bsh[512];
    __shared__ f4 Csh[512];
    int blk = blockIdx.x;
    int chgrp = blk & 15;
    int bg = blk >> 4;
    int g = bg % G_DIM;
    int b = bg / G_DIM;
    int tid = (int)threadIdx.x;

    const f4* Bg = (const f4*)(Bsw + ((size_t)bg * L_LEN + chgrp * 128) * N_DIM);
    const f4* Cg = (const f4*)(Csw + ((size_t)bg * L_LEN + chgrp * 128) * N_DIM);
    for (int i = tid; i < 512; i += 192) { Bsh[i] = Bg[i]; Csh[i] = Cg[i]; }
    __syncthreads();

    int chl = tid / 96;
    int c = tid % 96;
    int ch = chgrp * 2 + chl;
    int bgc = bg * C_DIM + c;
    const bool rev = (g >= 6);
    int gu = rev ? (g - 6) : g;

    float a2[N_DIM];
    {
        const f4* Ap = (const f4*)(A_logs + ((size_t)g * C_DIM + c) * N_DIM);
        f4 Av[4] = { Ap[0], Ap[1], Ap[2], Ap[3] };
#pragma unroll
        for (int n = 0; n < N_DIM; ++n)
            a2[n] = -__expf(Av[n >> 2][n & 3]) * 1.44269504f;
    }
    float dsc = Ds[g * C_DIM + c];

    const float* drow = delta + (size_t)bgc * L_LEN;
    const float* urow = u6 + (((size_t)b * 6 + gu) * C_DIM + c) * L_LEN;
    float* yrow = yss + (size_t)bgc * L_LEN;

    float h[N_DIM];
    {
        const f4* Hp = (const f4*)(hstart + ((size_t)bgc * NCHUNK + ch) * N_DIM);
        f4 Hv[4] = { Hp[0], Hp[1], Hp[2], Hp[3] };
#pragma unroll
        for (int n = 0; n < N_DIM; ++n) h[n] = Hv[n >> 2][n & 3];
    }

    const int LOFF = ch * CLEN;
#pragma unroll 2
    for (int l4 = 0; l4 < CLEN; l4 += 4) {
        int lg = LOFF + l4;
        f4 d4 = *(const f4*)(drow + lg);
        f4 u4 = rev ? *(const f4*)(urow + (L_LEN - 4 - lg)) : *(const f4*)(urow + lg);
        f4 y4;
#pragma unroll
        for (int j = 0; j < 4; ++j) {
            float d = d4[j];
            float uu = rev ? u4[3 - j] : u4[j];
            float du = d * uu;
            const f4* Bl = Bsh + (size_t)(chl * CLEN + l4 + j) * 4;
            const f4* Cl = Csh + (size_t)(chl * CLEN + l4 + j) * 4;
            f4 Bv[4] = { Bl[0], Bl[1], Bl[2], Bl[3] };
            f4 Cv[4] = { Cl[0], Cl[1], Cl[2], Cl[3] };
            float y = dsc * uu;
#pragma unroll
            for (int n = 0; n < N_DIM; ++n) {
                float e = exp2f(d * a2[n]);
                h[n] = fmaf(h[n], e, du * Bv[n >> 2][n & 3]);
                y = fmaf(h[n], Cv[n >> 2][n & 3], y);
            }
            y4[j] = y;
        }
        *(f4*)(yrow + lg) = y4;
    }
}

// ---------------- K3: fold (un-scan) + LayerNorm, fused ----------------
__global__ __launch_bounds__(256) void k3_out(
    const float* __restrict__ yss, const float* __restrict__ nw,
    const float* __restrict__ nb, float* __restrict__ out)
{
    __shared__ float tA[32][97];
    __shared__ float tB[32][97];
    __shared__ float ps[4][8][32];
    __shared__ float stat[4][32];

    int blk = blockIdx.x;
    int h = blk & 31;
    int bs = blk >> 5;
    int so = bs & 1;
    int b = bs >> 1;
    int w = threadIdx.x & 31;
    int cg = threadIdx.x >> 5;
    int l0 = (h * 32 + w) * 2;
    int l1 = (w * 32 + h) * 2;

    auto Yp = [&](int g, int c) {
        return yss + (((size_t)b * 12 + g) * C_DIM + c) * L_LEN;
    };

    float sA = 0, qA = 0, sB = 0, qB = 0;
    for (int j = 0; j < 12; ++j) {
        int c = cg * 12 + j;
        f2 f0 = *(const f2*)(Yp(so, c) + l0);
        f2 r0 = *(const f2*)(Yp(6 + so, c) + (2046 - l0));
        f2 f1 = *(const f2*)(Yp(3 + so, c) + l1);
        f2 r1 = *(const f2*)(Yp(9 + so, c) + (2046 - l1));
        float ys0_a = f0.x + r0.y;
        float ys0_b = f0.y + r0.x;
        float ys1_a = f1.x + r1.y;
        float ys1_b = f1.y + r1.x;
        float yv = ys0_b + ys1_b;
        float dv = ys0_a + ys1_a;
        tA[w][c] = yv; tB[w][c] = dv;
        sA += yv; qA += yv * yv; sB += dv; qB += dv * dv;
    }
    ps[0][cg][w] = sA; ps[1][cg][w] = qA; ps[2][cg][w] = sB; ps[3][cg][w] = qB;
    __syncthreads();
    if (threadIdx.x < 32) {
        int ww = threadIdx.x;
        float t0 = 0, t1 = 0, t2 = 0, t3 = 0;
#pragma unroll
        for (int q = 0; q < 8; ++q) {
            t0 += ps[0][q][ww]; t1 += ps[1][q][ww];
            t2 += ps[2][q][ww]; t3 += ps[3][q][ww];
        }
        float muA = t0 * (1.f / 96.f), eqA = t1 * (1.f / 96.f);
        float muB = t2 * (1.f / 96.f), eqB = t3 * (1.f / 96.f);
        stat[0][ww] = muA; stat[1][ww] = rsqrtf(eqA - muA * muA + 1e-5f);
        stat[2][ww] = muB; stat[3][ww] = rsqrtf(eqB - muB * muB + 1e-5f);
    }
    __syncthreads();
    size_t obase = (size_t)blk * 3072;
    for (int e = threadIdx.x; e < 3072; e += 256) {
        int ww = e / 96, c = e % 96;
        float wc = nw[c], bc = nb[c];
        out[obase + e] = (tA[ww][c] - stat[0][ww]) * stat[1][ww] * wc + bc;
        out[2 * 786432 + obase + e] = (tB[ww][c] - stat[2][ww]) * stat[3][ww] * wc + bc;
    }
    __syncthreads();

    float sC = 0, qC = 0;
    for (int j = 0; j < 12; ++j) {
        int c = cg * 12 + j;
        f2 f0 = *(const f2*)(Yp(2, c) + l0);
        f2 r0 = *(const f2*)(Yp(8, c) + (2046 - l0));
        f2 f1 = *(const f2*)(Yp(5, c) + l1);
        f2 r1 = *(const f2*)(Yp(11, c) + (2046 - l1));
        float v;
        if (so == 0) v = (f0.x + r0.y) + (f1.x + r1.y);
        else         v = (f0.y + r0.x) + (f1.y + r1.x);
        tA[w][c] = v; sC += v; qC += v * v;
    }
    ps[0][cg][w] = sC; ps[1][cg][w] = qC;
    __syncthreads();
    if (threadIdx.x < 32) {
        int ww = threadIdx.x;
        float t0 = 0, t1 = 0;
#pragma unroll
        for (int q = 0; q < 8; ++q) { t0 += ps[0][q][ww]; t1 += ps[1][q][ww]; }
        float mu = t0 * (1.f / 96.f), eq = t1 * (1.f / 96.f);
        stat[0][ww] = mu; stat[1][ww] = rsqrtf(eq - mu * mu + 1e-5f);
    }
    __syncthreads();
    for (int e = threadIdx.x; e < 3072; e += 256) {
        int ww = e / 96, c = e % 96;
        out[786432 + obase + e] = (tA[ww][c] - stat[0][ww]) * stat[1][ww] * nw[c] + nb[c];
    }
}

extern "C" void kernel_launch(void* const* d_in, const int* in_sizes, int n_in,
                              void* d_out, int out_size, void* d_ws, size_t ws_size,
                              hipStream_t stream)
{
    const float* x = (const float*)d_in[0];
    const float* xpw = (const float*)d_in[1];
    const float* dtw = (const float*)d_in[2];
    const float* dtb = (const float*)d_in[3];
    const float* A_logs = (const float*)d_in[4];
    const float* Ds = (const float*)d_in[5];
    const float* nw = (const float*)d_in[6];
    const float* nb = (const float*)d_in[7];
    float* out = (float*)d_out;

    float* ws = (float*)d_ws;
    float* delta = ws;                 // SZ_DELTA
    float* Bsw = delta + SZ_DELTA;     // SZ_BC
    float* Csw = Bsw + SZ_BC;          // SZ_BC
    float* u6 = Csw + SZ_BC;           // SZ_U6
    float* yss = u6 + SZ_U6;           // SZ_DELTA
    float* hend = yss + SZ_DELTA;      // SZ_H
    float* prodE = hend + SZ_H;        // SZ_H (then reused as hstart)
    float* xT = prodE + SZ_H;          // SZ_X

    k0_xT<<<dim3(768), dim3(256), 0, stream>>>(x, xT);
    k1_proj<<<dim3(48 * 32), dim3(256), 0, stream>>>(x, xT, xpw, dtw, dtb, delta, Bsw, Csw, u6);
    k2_scanA<<<dim3(48 * 16), dim3(192), 0, stream>>>(delta, Bsw, u6, A_logs, hend, prodE);
    k2_fix<<<dim3(288), dim3(256), 0, stream>>>(hend, prodE);
    k2_scanC<<<dim3(48 * 16), dim3(192), 0, stream>>>(delta, Bsw, Csw, u6, A_logs, Ds, prodE, yss);
    k3_out<<<dim3(256), dim3(256), 0, stream>>>(yss, nw, nb, out);
}

// Round 6
// 243.331 us; speedup vs baseline: 1.9979x; 1.2506x over previous
//
#include <hip/hip_runtime.h>
#include <math.h>

typedef float f4 __attribute__((ext_vector_type(4)));

#define L_LEN 2048
#define C_DIM 96
#define N_DIM 16
#define P_DIM 38
#define R_DIM 6
#define G_DIM 12
#define B_DIM 4
#define NCHUNK 32
#define CLEN 64
#define BGC (B_DIM * G_DIM * C_DIM) // 4608

// workspace layout (floats)
#define SZ_DELTA (B_DIM * G_DIM * C_DIM * L_LEN) // 9437184
#define SZ_BC (B_DIM * G_DIM * N_DIM * L_LEN)    // 1572864
#define SZ_U6 (B_DIM * 6 * C_DIM * L_LEN)        // 4718592
#define SZ_H (BGC * NCHUNK * N_DIM)              // 2359296
#define SZ_X (B_DIM * 2 * C_DIM * 1024)          // 786432

// ---------------- K0: transpose x (H<->W) for odd-k coalescing ----------------
__global__ __launch_bounds__(256) void k0_xT(
    const float* __restrict__ x, float* __restrict__ xT)
{
    __shared__ float t[32][33];
    int img = blockIdx.x; // (b,s,c) image, 768 total
    const float* src = x + (size_t)img * 1024;
    float* dst = xT + (size_t)img * 1024;
    int tx = threadIdx.x & 31, ty = threadIdx.x >> 5;
#pragma unroll
    for (int r = 0; r < 32; r += 8) t[ty + r][tx] = src[(ty + r) * 32 + tx];
    __syncthreads();
#pragma unroll
    for (int r = 0; r < 32; r += 8) dst[(ty + r) * 32 + tx] = t[tx][ty + r];
}

// ---------------- K1: cross-scan gather + projections (LDS-tiled GEMM) ----------------
// Outputs: deltaT [bg][l][c], u6T [b6g][l][c], B/C [bg][l][n].
__global__ __launch_bounds__(256) void k1_proj(
    const float* __restrict__ x, const float* __restrict__ xT,
    const float* __restrict__ xpw, const float* __restrict__ dtw,
    const float* __restrict__ dtb, float* __restrict__ deltaT,
    float* __restrict__ Bsw, float* __restrict__ Csw, float* __restrict__ u6T)
{
    __shared__ float Vsh[C_DIM * 65]; // padded: [c][65] over ll
    __shared__ float As[R_DIM * 64];

    int blk = blockIdx.x;          // bg*32 + ltile
    int ltile = blk & 31;
    int bg = blk >> 5;             // 0..47
    int g = bg % G_DIM, b = bg / G_DIM;
    int k = g / 3, s = g % 3;
    int l0 = ltile * 64;
    int tid = (int)threadIdx.x;

    const float* xb = ((k & 1) ? xT : x) + (size_t)b * 2 * C_DIM * 1024;

    // ---- stage V (lanes vary ll: coalesced x reads) ----
    for (int idx = tid; idx < C_DIM * 64; idx += 256) {
        int c = idx >> 6, ll = idx & 63;
        int l = l0 + ll;
        int lf = (k < 2) ? l : (2047 - l);
        int s2 = lf & 1, pp = lf >> 1;
        float x0 = xb[(size_t)c * 1024 + pp];
        float x1 = xb[(size_t)(C_DIM + c) * 1024 + pp];
        float v;
        if (s == 2)  v = s2 ? x1 : x0;
        else if (s2) v = s ? x1 : x0;
        else         v = s ? (x1 - x0) : (x0 - x1);
        Vsh[c * 65 + ll] = v;
    }
    __syncthreads();

    // ---- u6T write, coalesced over c (g<6 only) ----
    if (g < 6) {
        size_t ub = ((size_t)(b * 6 + g) * L_LEN + l0) * C_DIM;
        for (int e = tid; e < C_DIM * 64; e += 256) {
            int lidx = e / 96, c = e % 96;
            u6T[ub + (size_t)lidx * C_DIM + c] = Vsh[c * 65 + lidx];
        }
    }

    // ---- register GEMM: acc[p] = sum_c w[p][c] * V[c][ll] ----
    int ll = tid & 63, pg = tid >> 6;
    int P0 = pg * 10;
    int PN = (pg == 3) ? 8 : 10;
    const float* wp = xpw + (size_t)g * P_DIM * C_DIM + (size_t)P0 * C_DIM;

    float acc[10];
#pragma unroll
    for (int p = 0; p < 10; ++p) acc[p] = 0.f;

    for (int cb = 0; cb < C_DIM; cb += 16) {
        float vc[16];
#pragma unroll
        for (int i = 0; i < 16; ++i) vc[i] = Vsh[(cb + i) * 65 + ll];
#pragma unroll
        for (int p = 0; p < 10; ++p) {
            if (p < PN) {
#pragma unroll
                for (int i = 0; i < 16; ++i)
                    acc[p] = fmaf(wp[p * C_DIM + cb + i], vc[i], acc[p]);
            }
        }
    }

    // ---- write B/C from regs; stage dts rows to LDS ----
    size_t lbase = ((size_t)bg * L_LEN + l0 + ll) * N_DIM;
#pragma unroll
    for (int p = 0; p < 10; ++p) {
        int pa = P0 + p;
        if (p < PN && pa >= 6) {
            if (pa < 22) Bsw[lbase + (pa - 6)] = acc[p];
            else         Csw[lbase + (pa - 22)] = acc[p];
        }
    }
    if (pg == 0) {
#pragma unroll
        for (int p = 0; p < 6; ++p) As[p * 64 + ll] = acc[p];
    }
    __syncthreads();

    // ---- delta: dt-proj + bias + softplus, coalesced over c ----
    const float* wd = dtw + (size_t)g * C_DIM * R_DIM;
    const float* bias = dtb + g * C_DIM;
    size_t db = ((size_t)bg * L_LEN + l0) * C_DIM;
    for (int e = tid; e < C_DIM * 64; e += 256) {
        int lidx = e / 96, c = e % 96;
        float dsum = bias[c];
#pragma unroll
        for (int r = 0; r < R_DIM; ++r) dsum = fmaf(As[r * 64 + lidx], wd[c * R_DIM + r], dsum);
        float sp = (dsum > 20.f) ? dsum : log1pf(__expf(dsum));
        deltaT[db + (size_t)lidx * C_DIM + c] = sp;
    }
}

// ---------------- K2: chunk-parallel scan, [l][c] layouts ----------------
// Pass A: per chunk with h0=0, compute h_end[16] and P[16]=prod(e).
__global__ __launch_bounds__(192) void k2_scanA(
    const float* __restrict__ deltaT, const float* __restrict__ Bsw,
    const float* __restrict__ u6T, const float* __restrict__ A_logs,
    float* __restrict__ hend, float* __restrict__ prodE)
{
    __shared__ f4 Bsh[512]; // 128 l x 16 n
    int blk = blockIdx.x;
    int chgrp = blk & 15;
    int bg = blk >> 4;
    int g = bg % G_DIM;
    int b = bg / G_DIM;
    int tid = (int)threadIdx.x;

    const f4* Bg = (const f4*)(Bsw + ((size_t)bg * L_LEN + chgrp * 128) * N_DIM);
    for (int i = tid; i < 512; i += 192) Bsh[i] = Bg[i];
    __syncthreads();

    int chl = tid / 96;
    int c = tid % 96;
    int ch = chgrp * 2 + chl;
    int bgc = bg * C_DIM + c;
    const bool rev = (g >= 6);
    int gu = rev ? (g - 6) : g;

    float a2[N_DIM];
    {
        const f4* Ap = (const f4*)(A_logs + ((size_t)g * C_DIM + c) * N_DIM);
        f4 Av[4] = { Ap[0], Ap[1], Ap[2], Ap[3] };
#pragma unroll
        for (int n = 0; n < N_DIM; ++n)
            a2[n] = -__expf(Av[n >> 2][n & 3]) * 1.44269504f;
    }

    const int LOFF = ch * CLEN;
    const float* dp = deltaT + ((size_t)bg * L_LEN + LOFF) * C_DIM + c;
    const float* up;
    int ustep;
    if (rev) { up = u6T + ((size_t)(b * 6 + gu) * L_LEN + (2047 - LOFF)) * C_DIM + c; ustep = -C_DIM; }
    else     { up = u6T + ((size_t)(b * 6 + gu) * L_LEN + LOFF) * C_DIM + c; ustep = C_DIM; }

    float h[N_DIM], P[N_DIM];
#pragma unroll
    for (int n = 0; n < N_DIM; ++n) { h[n] = 0.f; P[n] = 1.f; }

    float dbuf[4], ubuf[4];
#pragma unroll
    for (int j = 0; j < 4; ++j) { dbuf[j] = dp[j * C_DIM]; ubuf[j] = up[j * ustep]; }

    for (int jj = 0; jj < CLEN; jj += 4) {
        int nx = (jj + 4 < CLEN) ? jj + 4 : jj;
        float dn[4], un[4];
#pragma unroll
        for (int j = 0; j < 4; ++j) { dn[j] = dp[(nx + j) * C_DIM]; un[j] = up[(nx + j) * ustep]; }
#pragma unroll
        for (int j = 0; j < 4; ++j) {
            float d = dbuf[j];
            float du = d * ubuf[j];
            const f4* Bl = Bsh + (size_t)(chl * CLEN + jj + j) * 4;
            f4 Bv[4] = { Bl[0], Bl[1], Bl[2], Bl[3] };
#pragma unroll
            for (int n = 0; n < N_DIM; ++n) {
                float e = exp2f(d * a2[n]);
                P[n] *= e;
                h[n] = fmaf(h[n], e, du * Bv[n >> 2][n & 3]);
            }
        }
#pragma unroll
        for (int j = 0; j < 4; ++j) { dbuf[j] = dn[j]; ubuf[j] = un[j]; }
    }
    float* hp = hend + ((size_t)bgc * NCHUNK + ch) * N_DIM;
    float* pp = prodE + ((size_t)bgc * NCHUNK + ch) * N_DIM;
#pragma unroll
    for (int q = 0; q < 4; ++q) {
        f4 hv = { h[q * 4], h[q * 4 + 1], h[q * 4 + 2], h[q * 4 + 3] };
        f4 pv = { P[q * 4], P[q * 4 + 1], P[q * 4 + 2], P[q * 4 + 3] };
        *(f4*)(hp + q * 4) = hv;
        *(f4*)(pp + q * 4) = pv;
    }
}

// Pass B: compose chunk propagators. Overwrites prodE with hstart (in place).
__global__ __launch_bounds__(256) void k2_fix(
    const float* __restrict__ hend, float* prodE_hstart)
{
    int t = blockIdx.x * 256 + (int)threadIdx.x; // 73728
    int n = t & 15;
    int bgc = t >> 4;
    float h = 0.f;
    for (int ch = 0; ch < NCHUNK; ++ch) {
        size_t idx = ((size_t)bgc * NCHUNK + ch) * N_DIM + n;
        float Pv = prodE_hstart[idx];
        float he = hend[idx];
        prodE_hstart[idx] = h;
        h = fmaf(h, Pv, he);
    }
}

// Pass C: exact recurrence from hstart, writes yT [bg][l][c] (+Ds*u folded).
__global__ __launch_bounds__(192) void k2_scanC(
    const float* __restrict__ deltaT, const float* __restrict__ Bsw,
    const float* __restrict__ Csw, const float* __restrict__ u6T,
    const float* __restrict__ A_logs, const float* __restrict__ Ds,
    const float* __restrict__ hstart, float* __restrict__ yssT)
{
    __shared__ f4 Bsh[512];
    __shared__ f4 Csh[512];
    int blk = blockIdx.x;
    int chgrp = blk & 15;
    int bg = blk >> 4;
    int g = bg % G_DIM;
    int b = bg / G_DIM;
    int tid = (int)threadIdx.x;

    const f4* Bg = (const f4*)(Bsw + ((size_t)bg * L_LEN + chgrp * 128) * N_DIM);
    const f4* Cg = (const f4*)(Csw + ((size_t)bg * L_LEN + chgrp * 128) * N_DIM);
    for (int i = tid; i < 512; i += 192) { Bsh[i] = Bg[i]; Csh[i] = Cg[i]; }
    __syncthreads();

    int chl = tid / 96;
    int c = tid % 96;
    int ch = chgrp * 2 + chl;
    int bgc = bg * C_DIM + c;
    const bool rev = (g >= 6);
    int gu = rev ? (g - 6) : g;

    float a2[N_DIM];
    {
        const f4* Ap = (const f4*)(A_logs + ((size_t)g * C_DIM + c) * N_DIM);
        f4 Av[4] = { Ap[0], Ap[1], Ap[2], Ap[3] };
#pragma unroll
        for (int n = 0; n < N_DIM; ++n)
            a2[n] = -__expf(Av[n >> 2][n & 3]) * 1.44269504f;
    }
    float dsc = Ds[g * C_DIM + c];

    const int LOFF = ch * CLEN;
    const float* dp = deltaT + ((size_t)bg * L_LEN + LOFF) * C_DIM + c;
    const float* up;
    int ustep;
    if (rev) { up = u6T + ((size_t)(b * 6 + gu) * L_LEN + (2047 - LOFF)) * C_DIM + c; ustep = -C_DIM; }
    else     { up = u6T + ((size_t)(b * 6 + gu) * L_LEN + LOFF) * C_DIM + c; ustep = C_DIM; }
    float* yp = yssT + ((size_t)bg * L_LEN + LOFF) * C_DIM + c;

    float h[N_DIM];
    {
        const f4* Hp = (const f4*)(hstart + ((size_t)bgc * NCHUNK + ch) * N_DIM);
        f4 Hv[4] = { Hp[0], Hp[1], Hp[2], Hp[3] };
#pragma unroll
        for (int n = 0; n < N_DIM; ++n) h[n] = Hv[n >> 2][n & 3];
    }

    float dbuf[4], ubuf[4];
#pragma unroll
    for (int j = 0; j < 4; ++j) { dbuf[j] = dp[j * C_DIM]; ubuf[j] = up[j * ustep]; }

    for (int jj = 0; jj < CLEN; jj += 4) {
        int nx = (jj + 4 < CLEN) ? jj + 4 : jj;
        float dn[4], un[4];
#pragma unroll
        for (int j = 0; j < 4; ++j) { dn[j] = dp[(nx + j) * C_DIM]; un[j] = up[(nx + j) * ustep]; }
#pragma unroll
        for (int j = 0; j < 4; ++j) {
            float d = dbuf[j];
            float uu = ubuf[j];
            float du = d * uu;
            const f4* Bl = Bsh + (size_t)(chl * CLEN + jj + j) * 4;
            const f4* Cl = Csh + (size_t)(chl * CLEN + jj + j) * 4;
            f4 Bv[4] = { Bl[0], Bl[1], Bl[2], Bl[3] };
            f4 Cv[4] = { Cl[0], Cl[1], Cl[2], Cl[3] };
            float y = dsc * uu;
#pragma unroll
            for (int n = 0; n < N_DIM; ++n) {
                float e = exp2f(d * a2[n]);
                h[n] = fmaf(h[n], e, du * Bv[n >> 2][n & 3]);
                y = fmaf(h[n], Cv[n >> 2][n & 3], y);
            }
            yp[(jj + j) * C_DIM] = y;
        }
#pragma unroll
        for (int j = 0; j < 4; ++j) { dbuf[j] = dn[j]; ubuf[j] = un[j]; }
    }
}

// ---------------- K3: fold (un-scan) + LayerNorm, fused ([l][c] input) ----------------
__global__ __launch_bounds__(256) void k3_out(
    const float* __restrict__ yssT, const float* __restrict__ nw,
    const float* __restrict__ nb, float* __restrict__ out)
{
    __shared__ float tA[32][97];
    __shared__ float tB[32][97];
    __shared__ float ps[4][8][32];
    __shared__ float stat[4][32];

    int blk = blockIdx.x;
    int h = blk & 31;
    int bs = blk >> 5;
    int so = bs & 1;
    int b = bs >> 1;
    int tid = (int)threadIdx.x;

    auto Y = [&](int g) { return yssT + (size_t)(b * 12 + g) * L_LEN * C_DIM; };
    const float* Y0  = Y(so);
    const float* Y0r = Y(6 + so);
    const float* Y1  = Y(3 + so);
    const float* Y1r = Y(9 + so);

    // ---- phase 1: thread owns (par,w,c); 4 coalesced stream reads ----
#pragma unroll 2
    for (int it = 0; it < 24; ++it) {
        int idx = tid + it * 256;
        int c = idx % 96, rest = idx / 96;  // rest in [0,64)
        int w = rest >> 1, par = rest & 1;
        int a0 = h * 64 + rest;             // = h*64 + 2w + par
        int a1 = w * 64 + 2 * h + par;
        float v = Y0[(size_t)a0 * C_DIM + c] + Y0r[(size_t)(2047 - a0) * C_DIM + c]
                + Y1[(size_t)a1 * C_DIM + c] + Y1r[(size_t)(2047 - a1) * C_DIM + c];
        if (par) tA[w][c] = v; else tB[w][c] = v;
    }
    __syncthreads();

    int w = tid & 31, cg = tid >> 5;
    float sA = 0, qA = 0, sB = 0, qB = 0;
#pragma unroll
    for (int j = 0; j < 12; ++j) {
        float yv = tA[w][cg * 12 + j], dv = tB[w][cg * 12 + j];
        sA += yv; qA += yv * yv; sB += dv; qB += dv * dv;
    }
    ps[0][cg][w] = sA; ps[1][cg][w] = qA; ps[2][cg][w] = sB; ps[3][cg][w] = qB;
    __syncthreads();
    if (tid < 32) {
        int ww = tid;
        float t0 = 0, t1 = 0, t2 = 0, t3 = 0;
#pragma unroll
        for (int q = 0; q < 8; ++q) {
            t0 += ps[0][q][ww]; t1 += ps[1][q][ww];
            t2 += ps[2][q][ww]; t3 += ps[3][q][ww];
        }
        float muA = t0 * (1.f / 96.f), eqA = t1 * (1.f / 96.f);
        float muB = t2 * (1.f / 96.f), eqB = t3 * (1.f / 96.f);
        stat[0][ww] = muA; stat[1][ww] = rsqrtf(eqA - muA * muA + 1e-5f);
        stat[2][ww] = muB; stat[3][ww] = rsqrtf(eqB - muB * muB + 1e-5f);
    }
    __syncthreads();
    size_t obase = (size_t)blk * 3072;
    for (int e = tid; e < 3072; e += 256) {
        int ww = e / 96, c = e % 96;
        float wc = nw[c], bc = nb[c];
        out[obase + e] = (tA[ww][c] - stat[0][ww]) * stat[1][ww] * wc + bc;
        out[2 * 786432 + obase + e] = (tB[ww][c] - stat[2][ww]) * stat[3][ww] * wc + bc;
    }
    __syncthreads();

    // ---- phase 2: y_com ----
    const float* Y2  = Y(2);
    const float* Y2r = Y(8);
    const float* Y3  = Y(5);
    const float* Y3r = Y(11);
#pragma unroll 2
    for (int it = 0; it < 12; ++it) {
        int idx = tid + it * 256;
        int c = idx % 96, w2 = idx / 96; // [0,32)
        int a0 = h * 64 + 2 * w2 + so;
        int a1 = w2 * 64 + 2 * h + so;
        float v = Y2[(size_t)a0 * C_DIM + c] + Y2r[(size_t)(2047 - a0) * C_DIM + c]
                + Y3[(size_t)a1 * C_DIM + c] + Y3r[(size_t)(2047 - a1) * C_DIM + c];
        tA[w2][c] = v;
    }
    __syncthreads();
    float sC = 0, qC = 0;
#pragma unroll
    for (int j = 0; j < 12; ++j) {
        float v = tA[w][cg * 12 + j];
        sC += v; qC += v * v;
    }
    ps[0][cg][w] = sC; ps[1][cg][w] = qC;
    __syncthreads();
    if (tid < 32) {
        int ww = tid;
        float t0 = 0, t1 = 0;
#pragma unroll
        for (int q = 0; q < 8; ++q) { t0 += ps[0][q][ww]; t1 += ps[1][q][ww]; }
        float mu = t0 * (1.f / 96.f), eq = t1 * (1.f / 96.f);
        stat[0][ww] = mu; stat[1][ww] = rsqrtf(eq - mu * mu + 1e-5f);
    }
    __syncthreads();
    for (int e = tid; e < 3072; e += 256) {
        int ww = e / 96, c = e % 96;
        out[786432 + obase + e] = (tA[ww][c] - stat[0][ww]) * stat[1][ww] * nw[c] + nb[c];
    }
}

extern "C" void kernel_launch(void* const* d_in, const int* in_sizes, int n_in,
                              void* d_out, int out_size, void* d_ws, size_t ws_size,
                              hipStream_t stream)
{
    const float* x = (const float*)d_in[0];
    const float* xpw = (const float*)d_in[1];
    const float* dtw = (const float*)d_in[2];
    const float* dtb = (const float*)d_in[3];
    const float* A_logs = (const float*)d_in[4];
    const float* Ds = (const float*)d_in[5];
    const float* nw = (const float*)d_in[6];
    const float* nb = (const float*)d_in[7];
    float* out = (float*)d_out;

    float* ws = (float*)d_ws;
    float* deltaT = ws;                // SZ_DELTA
    float* Bsw = deltaT + SZ_DELTA;    // SZ_BC
    float* Csw = Bsw + SZ_BC;          // SZ_BC
    float* u6T = Csw + SZ_BC;          // SZ_U6
    float* yssT = u6T + SZ_U6;         // SZ_DELTA
    float* hend = yssT + SZ_DELTA;     // SZ_H
    float* prodE = hend + SZ_H;        // SZ_H (then reused as hstart)
    float* xT = prodE + SZ_H;          // SZ_X

    k0_xT<<<dim3(768), dim3(256), 0, stream>>>(x, xT);
    k1_proj<<<dim3(48 * 32), dim3(256), 0, stream>>>(x, xT, xpw, dtw, dtb, deltaT, Bsw, Csw, u6T);
    k2_scanA<<<dim3(48 * 16), dim3(192), 0, stream>>>(deltaT, Bsw, u6T, A_logs, hend, prodE);
    k2_fix<<<dim3(288), dim3(256), 0, stream>>>(hend, prodE);
    k2_scanC<<<dim3(48 * 16), dim3(192), 0, stream>>>(deltaT, Bsw, Csw, u6T, A_logs, Ds, prodE, yssT);
    k3_out<<<dim3(256), dim3(256), 0, stream>>>(yssT, nw, nb, out);
}

// Round 7
// 208.609 us; speedup vs baseline: 2.3304x; 1.1664x over previous
//
#include <hip/hip_runtime.h>
#include <math.h>

typedef float f4 __attribute__((ext_vector_type(4)));
typedef float f2 __attribute__((ext_vector_type(2)));

#define L_LEN 2048
#define C_DIM 96
#define N_DIM 16
#define R_DIM 6
#define G_DIM 12
#define B_DIM 4
#define NCHUNK 32
#define CLEN 64
#define BGC (B_DIM * G_DIM * C_DIM) // 4608

// workspace layout (floats)
#define SZ_DTS (B_DIM * G_DIM * L_LEN * R_DIM)   // 589824
#define SZ_BC (B_DIM * G_DIM * N_DIM * L_LEN)    // 1572864
#define SZ_U6 (B_DIM * 6 * C_DIM * L_LEN)        // 4718592
#define SZ_Y (B_DIM * G_DIM * C_DIM * L_LEN)     // 9437184
#define SZ_H (BGC * NCHUNK * N_DIM)              // 2359296
#define SZ_X (B_DIM * 2 * C_DIM * 1024)          // 786432
#define SZ_WPAD (G_DIM * 40 * C_DIM)             // 46080

// ---------------- K0: transpose x (H<->W) for odd-k coalescing ----------------
__global__ __launch_bounds__(256) void k0_xT(
    const float* __restrict__ x, float* __restrict__ xT)
{
    __shared__ float t[32][33];
    int img = blockIdx.x; // (b,s,c) image, 768 total
    const float* src = x + (size_t)img * 1024;
    float* dst = xT + (size_t)img * 1024;
    int tx = threadIdx.x & 31, ty = threadIdx.x >> 5;
#pragma unroll
    for (int r = 0; r < 32; r += 8) t[ty + r][tx] = src[(ty + r) * 32 + tx];
    __syncthreads();
#pragma unroll
    for (int r = 0; r < 32; r += 8) dst[(ty + r) * 32 + tx] = t[tx][ty + r];
}

// ---------------- K0b: zero-pad x_proj_weight rows 38->40 ----------------
__global__ __launch_bounds__(256) void k0b_padw(
    const float* __restrict__ xpw, float* __restrict__ wpad)
{
    int i = blockIdx.x * 256 + (int)threadIdx.x; // < 46080
    if (i >= G_DIM * 40 * C_DIM) return;
    int g = i / (40 * C_DIM);
    int rem = i - g * 40 * C_DIM;
    int p = rem / C_DIM, c = rem - (rem / C_DIM) * C_DIM;
    wpad[i] = (p < 38) ? xpw[((size_t)g * 38 + p) * C_DIM + c] : 0.f;
}

// ---------------- K1: paired cross-scan gather + projections ----------------
// block = (b, k<2, s, 64-l tile); computes g=k*3+s AND gh=g+6 (V reversal).
// Outputs: dtsT [bg][l][6], B/C [bg][l][16] (coalesced via LDS transpose),
// u6T [b6g][l][c].
__global__ __launch_bounds__(256) void k1_proj(
    const float* __restrict__ x, const float* __restrict__ xT,
    const float* __restrict__ wpad,
    float* __restrict__ dtsT, float* __restrict__ Bsw,
    float* __restrict__ Csw, float* __restrict__ u6T)
{
    __shared__ float Vsh[C_DIM * 68];
    __shared__ float Psh[40][68];

    int blk = blockIdx.x;      // bks*32 + ltile
    int ltile = blk & 31;
    int bks = blk >> 5;        // 0..23
    int s = bks % 3;
    int k = (bks / 3) & 1;
    int b = bks / 6;
    int g = k * 3 + s;         // 0..5
    int gh = g + 6;
    int l0 = ltile * 64;
    int l0h = (31 - ltile) * 64;
    int bg = b * G_DIM + g;
    int bgh = b * G_DIM + gh;
    int tid = (int)threadIdx.x;

    const float* xb = (k ? xT : x) + (size_t)b * 2 * C_DIM * 1024;

    // ---- stage V[c][ll] (f2 loads, f4 LDS writes) ----
#pragma unroll
    for (int j = 0; j < 6; ++j) {
        int e = tid + j * 256;       // < 1536
        int c = e >> 4;
        int llq = (e & 15) * 4;
        int pp = (l0 + llq) >> 1;
        f2 x0 = *(const f2*)(xb + (size_t)c * 1024 + pp);
        f2 x1 = *(const f2*)(xb + (size_t)(C_DIM + c) * 1024 + pp);
        f4 v;
        if (s == 2)      { v[0] = x0.x; v[1] = x1.x; v[2] = x0.y; v[3] = x1.y; }
        else if (s == 1) { v[0] = x1.x - x0.x; v[1] = x1.x; v[2] = x1.y - x0.y; v[3] = x1.y; }
        else             { v[0] = x0.x - x1.x; v[1] = x0.x; v[2] = x0.y - x1.y; v[3] = x0.y; }
        *(f4*)(Vsh + c * 68 + llq) = v;
    }
    __syncthreads();

    // ---- u6T[b6g][l][c] (coalesced f4, g<6 always here) ----
    {
        size_t ub = ((size_t)(b * 6 + g) * L_LEN + l0) * C_DIM;
#pragma unroll
        for (int j = 0; j < 6; ++j) {
            int e = tid + j * 256;
            int lidx = e / 24;
            int c4 = (e - lidx * 24) * 4;
            f4 v = { Vsh[(c4 + 0) * 68 + lidx], Vsh[(c4 + 1) * 68 + lidx],
                     Vsh[(c4 + 2) * 68 + lidx], Vsh[(c4 + 3) * 68 + lidx] };
            *(f4*)(u6T + ub + (size_t)lidx * C_DIM + c4) = v;
        }
    }

    // ---- register GEMM for g and gh (weights via scalar f4 loads) ----
    int ll = tid & 63;
    int P0 = __builtin_amdgcn_readfirstlane((tid >> 6) * 10);
    const float* wp = wpad + (size_t)g * 3840 + (size_t)P0 * C_DIM;
    const float* wph = wpad + (size_t)gh * 3840 + (size_t)P0 * C_DIM;

    float acc[10], acch[10];
#pragma unroll
    for (int p = 0; p < 10; ++p) { acc[p] = 0.f; acch[p] = 0.f; }

    for (int cb = 0; cb < C_DIM; cb += 8) {
        float vc[8], vch[8];
#pragma unroll
        for (int i = 0; i < 8; ++i) {
            vc[i] = Vsh[(cb + i) * 68 + ll];
            vch[i] = Vsh[(cb + i) * 68 + 63 - ll];
        }
#pragma unroll
        for (int p = 0; p < 10; ++p) {
#pragma unroll
            for (int q = 0; q < 2; ++q) {
                f4 w = *(const f4*)(wp + p * C_DIM + cb + q * 4);
                f4 wh = *(const f4*)(wph + p * C_DIM + cb + q * 4);
#pragma unroll
                for (int i = 0; i < 4; ++i) {
                    acc[p] = fmaf(w[i], vc[q * 4 + i], acc[p]);
                    acch[p] = fmaf(wh[i], vch[q * 4 + i], acch[p]);
                }
            }
        }
    }

    // ---- transpose via Psh, coalesced stores (g then gh) ----
#pragma unroll
    for (int gg = 0; gg < 2; ++gg) {
        __syncthreads();
#pragma unroll
        for (int p = 0; p < 10; ++p) Psh[P0 + p][ll] = gg ? acch[p] : acc[p];
        __syncthreads();
        int lb = gg ? l0h : l0;
        int bgx = gg ? bgh : bg;
        int q = tid & 3, lx = tid >> 2;
        f4 bv = { Psh[6 + q * 4 + 0][lx], Psh[6 + q * 4 + 1][lx],
                  Psh[6 + q * 4 + 2][lx], Psh[6 + q * 4 + 3][lx] };
        *(f4*)(Bsw + ((size_t)bgx * L_LEN + lb + lx) * N_DIM + q * 4) = bv;
        f4 cv = { Psh[22 + q * 4 + 0][lx], Psh[22 + q * 4 + 1][lx],
                  Psh[22 + q * 4 + 2][lx], Psh[22 + q * 4 + 3][lx] };
        *(f4*)(Csw + ((size_t)bgx * L_LEN + lb + lx) * N_DIM + q * 4) = cv;
        for (int e = tid; e < 64 * R_DIM; e += 256) {
            int lx2 = e / 6, r = e - (e / 6) * 6;
            dtsT[((size_t)bgx * L_LEN + lb + lx2) * R_DIM + r] = Psh[r][lx2];
        }
    }
}

// ---------------- K2: chunk-parallel scan, delta recomputed on the fly ----------------
__device__ __forceinline__ float softplus_f(float x)
{
    float sp = __logf(1.f + __expf(x));
    return (x > 60.f) ? x : sp;
}

// Pass A: per chunk with h0=0, compute h_end[16] and prodE[16]=exp2(a2*S).
__global__ __launch_bounds__(192) void k2_scanA(
    const float* __restrict__ dtsT, const float* __restrict__ Bsw,
    const float* __restrict__ u6T, const float* __restrict__ A_logs,
    const float* __restrict__ dtw, const float* __restrict__ dtb,
    float* __restrict__ hend, float* __restrict__ prodE)
{
    __shared__ f4 Bsh[512];     // 128 l x 16 n
    __shared__ float Dsh[768];  // 128 l x 6
    int blk = blockIdx.x;
    int chgrp = blk & 15;
    int bg = blk >> 4;
    int g = bg % G_DIM;
    int b = bg / G_DIM;
    int tid = (int)threadIdx.x;

    const f4* Bg = (const f4*)(Bsw + ((size_t)bg * L_LEN + chgrp * 128) * N_DIM);
    for (int i = tid; i < 512; i += 192) Bsh[i] = Bg[i];
    const float* Dg = dtsT + ((size_t)bg * L_LEN + chgrp * 128) * R_DIM;
    for (int i = tid; i < 768; i += 192) Dsh[i] = Dg[i];
    __syncthreads();

    int chl = tid / 96;
    int c = tid % 96;
    int ch = chgrp * 2 + chl;
    int bgc = bg * C_DIM + c;
    const bool rev = (g >= 6);
    int gu = rev ? (g - 6) : g;

    float a2[N_DIM];
    {
        const f4* Ap = (const f4*)(A_logs + ((size_t)g * C_DIM + c) * N_DIM);
        f4 Av[4] = { Ap[0], Ap[1], Ap[2], Ap[3] };
#pragma unroll
        for (int n = 0; n < N_DIM; ++n)
            a2[n] = -__expf(Av[n >> 2][n & 3]) * 1.44269504f;
    }
    float wdr[R_DIM];
    {
        const float* wdp = dtw + ((size_t)g * C_DIM + c) * R_DIM;
#pragma unroll
        for (int r = 0; r < R_DIM; ++r) wdr[r] = wdp[r];
    }
    float bias = dtb[g * C_DIM + c];

    const int LOFF = ch * CLEN;
    const float* up;
    int ustep;
    if (rev) { up = u6T + ((size_t)(b * 6 + gu) * L_LEN + (2047 - LOFF)) * C_DIM + c; ustep = -C_DIM; }
    else     { up = u6T + ((size_t)(b * 6 + gu) * L_LEN + LOFF) * C_DIM + c; ustep = C_DIM; }

    float h[N_DIM];
#pragma unroll
    for (int n = 0; n < N_DIM; ++n) h[n] = 0.f;
    float S = 0.f;

    float ubuf[4];
#pragma unroll
    for (int j = 0; j < 4; ++j) ubuf[j] = up[j * ustep];

    for (int jj = 0; jj < CLEN; jj += 4) {
        int nx = (jj + 4 < CLEN) ? jj + 4 : jj;
        float un[4];
#pragma unroll
        for (int j = 0; j < 4; ++j) un[j] = up[(nx + j) * ustep];
#pragma unroll
        for (int j = 0; j < 4; ++j) {
            int li = chl * CLEN + jj + j;
            float dt_ = bias;
#pragma unroll
            for (int r = 0; r < R_DIM; ++r) dt_ = fmaf(Dsh[li * R_DIM + r], wdr[r], dt_);
            float d = softplus_f(dt_);
            S += d;
            float du = d * ubuf[j];
            const f4* Bl = Bsh + (size_t)li * 4;
            f4 Bv[4] = { Bl[0], Bl[1], Bl[2], Bl[3] };
#pragma unroll
            for (int n = 0; n < N_DIM; ++n) {
                float e = exp2f(d * a2[n]);
                h[n] = fmaf(h[n], e, du * Bv[n >> 2][n & 3]);
            }
        }
#pragma unroll
        for (int j = 0; j < 4; ++j) ubuf[j] = un[j];
    }
    float* hp = hend + ((size_t)bgc * NCHUNK + ch) * N_DIM;
    float* pp = prodE + ((size_t)bgc * NCHUNK + ch) * N_DIM;
#pragma unroll
    for (int q = 0; q < 4; ++q) {
        f4 hv = { h[q * 4], h[q * 4 + 1], h[q * 4 + 2], h[q * 4 + 3] };
        f4 pv = { exp2f(a2[q * 4] * S), exp2f(a2[q * 4 + 1] * S),
                  exp2f(a2[q * 4 + 2] * S), exp2f(a2[q * 4 + 3] * S) };
        *(f4*)(hp + q * 4) = hv;
        *(f4*)(pp + q * 4) = pv;
    }
}

// Pass B: compose chunk propagators. Overwrites prodE with hstart (in place).
__global__ __launch_bounds__(256) void k2_fix(
    const float* __restrict__ hend, float* prodE_hstart)
{
    int t = blockIdx.x * 256 + (int)threadIdx.x; // 73728
    int n = t & 15;
    int bgc = t >> 4;
    float h = 0.f;
    for (int ch = 0; ch < NCHUNK; ++ch) {
        size_t idx = ((size_t)bgc * NCHUNK + ch) * N_DIM + n;
        float Pv = prodE_hstart[idx];
        float he = hend[idx];
        prodE_hstart[idx] = h;
        h = fmaf(h, Pv, he);
    }
}

// Pass C: exact recurrence from hstart, writes yT [bg][l][c] (+Ds*u folded).
__global__ __launch_bounds__(192) void k2_scanC(
    const float* __restrict__ dtsT, const float* __restrict__ Bsw,
    const float* __restrict__ Csw, const float* __restrict__ u6T,
    const float* __restrict__ A_logs, const float* __restrict__ Ds,
    const float* __restrict__ dtw, const float* __restrict__ dtb,
    const float* __restrict__ hstart, float* __restrict__ yssT)
{
    __shared__ f4 Bsh[512];
    __shared__ f4 Csh[512];
    __shared__ float Dsh[768];
    int blk = blockIdx.x;
    int chgrp = blk & 15;
    int bg = blk >> 4;
    int g = bg % G_DIM;
    int b = bg / G_DIM;
    int tid = (int)threadIdx.x;

    const f4* Bg = (const f4*)(Bsw + ((size_t)bg * L_LEN + chgrp * 128) * N_DIM);
    const f4* Cg = (const f4*)(Csw + ((size_t)bg * L_LEN + chgrp * 128) * N_DIM);
    for (int i = tid; i < 512; i += 192) { Bsh[i] = Bg[i]; Csh[i] = Cg[i]; }
    const float* Dg = dtsT + ((size_t)bg * L_LEN + chgrp * 128) * R_DIM;
    for (int i = tid; i < 768; i += 192) Dsh[i] = Dg[i];
    __syncthreads();

    int chl = tid / 96;
    int c = tid % 96;
    int ch = chgrp * 2 + chl;
    int bgc = bg * C_DIM + c;
    const bool rev = (g >= 6);
    int gu = rev ? (g - 6) : g;

    float a2[N_DIM];
    {
        const f4* Ap = (const f4*)(A_logs + ((size_t)g * C_DIM + c) * N_DIM);
        f4 Av[4] = { Ap[0], Ap[1], Ap[2], Ap[3] };
#pragma unroll
        for (int n = 0; n < N_DIM; ++n)
            a2[n] = -__expf(Av[n >> 2][n & 3]) * 1.44269504f;
    }
    float wdr[R_DIM];
    {
        const float* wdp = dtw + ((size_t)g * C_DIM + c) * R_DIM;
#pragma unroll
        for (int r = 0; r < R_DIM; ++r) wdr[r] = wdp[r];
    }
    float bias = dtb[g * C_DIM + c];
    float dsc = Ds[g * C_DIM + c];

    const int LOFF = ch * CLEN;
    const float* up;
    int ustep;
    if (rev) { up = u6T + ((size_t)(b * 6 + gu) * L_LEN + (2047 - LOFF)) * C_DIM + c; ustep = -C_DIM; }
    else     { up = u6T + ((size_t)(b * 6 + gu) * L_LEN + LOFF) * C_DIM + c; ustep = C_DIM; }
    float* yp = yssT + ((size_t)bg * L_LEN + LOFF) * C_DIM + c;

    float h[N_DIM];
    {
        const f4* Hp = (const f4*)(hstart + ((size_t)bgc * NCHUNK + ch) * N_DIM);
        f4 Hv[4] = { Hp[0], Hp[1], Hp[2], Hp[3] };
#pragma unroll
        for (int n = 0; n < N_DIM; ++n) h[n] = Hv[n >> 2][n & 3];
    }

    float ubuf[4];
#pragma unroll
    for (int j = 0; j < 4; ++j) ubuf[j] = up[j * ustep];

    for (int jj = 0; jj < CLEN; jj += 4) {
        int nx = (jj + 4 < CLEN) ? jj + 4 : jj;
        float un[4];
#pragma unroll
        for (int j = 0; j < 4; ++j) un[j] = up[(nx + j) * ustep];
#pragma unroll
        for (int j = 0; j < 4; ++j) {
            int li = chl * CLEN + jj + j;
            float dt_ = bias;
#pragma unroll
            for (int r = 0; r < R_DIM; ++r) dt_ = fmaf(Dsh[li * R_DIM + r], wdr[r], dt_);
            float d = softplus_f(dt_);
            float uu = ubuf[j];
            float du = d * uu;
            const f4* Bl = Bsh + (size_t)li * 4;
            const f4* Cl = Csh + (size_t)li * 4;
            f4 Bv[4] = { Bl[0], Bl[1], Bl[2], Bl[3] };
            f4 Cv[4] = { Cl[0], Cl[1], Cl[2], Cl[3] };
            float y = dsc * uu;
#pragma unroll
            for (int n = 0; n < N_DIM; ++n) {
                float e = exp2f(d * a2[n]);
                h[n] = fmaf(h[n], e, du * Bv[n >> 2][n & 3]);
                y = fmaf(h[n], Cv[n >> 2][n & 3], y);
            }
            yp[(jj + j) * C_DIM] = y;
        }
#pragma unroll
        for (int j = 0; j < 4; ++j) ubuf[j] = un[j];
    }
}

// ---------------- K3: fold (un-scan) + LayerNorm, fused ([l][c] input) ----------------
__global__ __launch_bounds__(256) void k3_out(
    const float* __restrict__ yssT, const float* __restrict__ nw,
    const float* __restrict__ nb, float* __restrict__ out)
{
    __shared__ float tA[32][97];
    __shared__ float tB[32][97];
    __shared__ float ps[4][8][32];
    __shared__ float stat[4][32];

    int blk = blockIdx.x;
    int h = blk & 31;
    int bs = blk >> 5;
    int so = bs & 1;
    int b = bs >> 1;
    int tid = (int)threadIdx.x;

    auto Y = [&](int g) { return yssT + (size_t)(b * 12 + g) * L_LEN * C_DIM; };
    const float* Y0 = Y(so);
    const float* Y0r = Y(6 + so);
    const float* Y1 = Y(3 + so);
    const float* Y1r = Y(9 + so);

#pragma unroll 2
    for (int it = 0; it < 24; ++it) {
        int idx = tid + it * 256;
        int c = idx % 96, rest = idx / 96;
        int w = rest >> 1, par = rest & 1;
        int a0 = h * 64 + rest;
        int a1 = w * 64 + 2 * h + par;
        float v = Y0[(size_t)a0 * C_DIM + c] + Y0r[(size_t)(2047 - a0) * C_DIM + c]
                + Y1[(size_t)a1 * C_DIM + c] + Y1r[(size_t)(2047 - a1) * C_DIM + c];
        if (par) tA[w][c] = v; else tB[w][c] = v;
    }
    __syncthreads();

    int w = tid & 31, cg = tid >> 5;
    float sA = 0, qA = 0, sB = 0, qB = 0;
#pragma unroll
    for (int j = 0; j < 12; ++j) {
        float yv = tA[w][cg * 12 + j], dv = tB[w][cg * 12 + j];
        sA += yv; qA += yv * yv; sB += dv; qB += dv * dv;
    }
    ps[0][cg][w] = sA; ps[1][cg][w] = qA; ps[2][cg][w] = sB; ps[3][cg][w] = qB;
    __syncthreads();
    if (tid < 32) {
        int ww = tid;
        float t0 = 0, t1 = 0, t2 = 0, t3 = 0;
#pragma unroll
        for (int q = 0; q < 8; ++q) {
            t0 += ps[0][q][ww]; t1 += ps[1][q][ww];
            t2 += ps[2][q][ww]; t3 += ps[3][q][ww];
        }
        float muA = t0 * (1.f / 96.f), eqA = t1 * (1.f / 96.f);
        float muB = t2 * (1.f / 96.f), eqB = t3 * (1.f / 96.f);
        stat[0][ww] = muA; stat[1][ww] = rsqrtf(eqA - muA * muA + 1e-5f);
        stat[2][ww] = muB; stat[3][ww] = rsqrtf(eqB - muB * muB + 1e-5f);
    }
    __syncthreads();
    size_t obase = (size_t)blk * 3072;
    for (int e = tid; e < 3072; e += 256) {
        int ww = e / 96, c = e % 96;
        float wc = nw[c], bc = nb[c];
        out[obase + e] = (tA[ww][c] - stat[0][ww]) * stat[1][ww] * wc + bc;
        out[2 * 786432 + obase + e] = (tB[ww][c] - stat[2][ww]) * stat[3][ww] * wc + bc;
    }
    __syncthreads();

    const float* Y2 = Y(2);
    const float* Y2r = Y(8);
    const float* Y3 = Y(5);
    const float* Y3r = Y(11);
#pragma unroll 2
    for (int it = 0; it < 12; ++it) {
        int idx = tid + it * 256;
        int c = idx % 96, w2 = idx / 96;
        int a0 = h * 64 + 2 * w2 + so;
        int a1 = w2 * 64 + 2 * h + so;
        float v = Y2[(size_t)a0 * C_DIM + c] + Y2r[(size_t)(2047 - a0) * C_DIM + c]
                + Y3[(size_t)a1 * C_DIM + c] + Y3r[(size_t)(2047 - a1) * C_DIM + c];
        tA[w2][c] = v;
    }
    __syncthreads();
    float sC = 0, qC = 0;
#pragma unroll
    for (int j = 0; j < 12; ++j) {
        float v = tA[w][cg * 12 + j];
        sC += v; qC += v * v;
    }
    ps[0][cg][w] = sC; ps[1][cg][w] = qC;
    __syncthreads();
    if (tid < 32) {
        int ww = tid;
        float t0 = 0, t1 = 0;
#pragma unroll
        for (int q = 0; q < 8; ++q) { t0 += ps[0][q][ww]; t1 += ps[1][q][ww]; }
        float mu = t0 * (1.f / 96.f), eq = t1 * (1.f / 96.f);
        stat[0][ww] = mu; stat[1][ww] = rsqrtf(eq - mu * mu + 1e-5f);
    }
    __syncthreads();
    for (int e = tid; e < 3072; e += 256) {
        int ww = e / 96, c = e % 96;
        out[786432 + obase + e] = (tA[ww][c] - stat[0][ww]) * stat[1][ww] * nw[c] + nb[c];
    }
}

extern "C" void kernel_launch(void* const* d_in, const int* in_sizes, int n_in,
                              void* d_out, int out_size, void* d_ws, size_t ws_size,
                              hipStream_t stream)
{
    const float* x = (const float*)d_in[0];
    const float* xpw = (const float*)d_in[1];
    const float* dtw = (const float*)d_in[2];
    const float* dtb = (const float*)d_in[3];
    const float* A_logs = (const float*)d_in[4];
    const float* Ds = (const float*)d_in[5];
    const float* nw = (const float*)d_in[6];
    const float* nb = (const float*)d_in[7];
    float* out = (float*)d_out;

    float* ws = (float*)d_ws;
    float* dtsT = ws;                  // SZ_DTS
    float* Bsw = dtsT + SZ_DTS;        // SZ_BC
    float* Csw = Bsw + SZ_BC;          // SZ_BC
    float* u6T = Csw + SZ_BC;          // SZ_U6
    float* yssT = u6T + SZ_U6;         // SZ_Y
    float* hend = yssT + SZ_Y;         // SZ_H
    float* prodE = hend + SZ_H;        // SZ_H (then reused as hstart)
    float* xT = prodE + SZ_H;          // SZ_X
    float* wpad = xT + SZ_X;           // SZ_WPAD

    k0_xT<<<dim3(768), dim3(256), 0, stream>>>(x, xT);
    k0b_padw<<<dim3(180), dim3(256), 0, stream>>>(xpw, wpad);
    k1_proj<<<dim3(24 * 32), dim3(256), 0, stream>>>(x, xT, wpad, dtsT, Bsw, Csw, u6T);
    k2_scanA<<<dim3(48 * 16), dim3(192), 0, stream>>>(dtsT, Bsw, u6T, A_logs, dtw, dtb, hend, prodE);
    k2_fix<<<dim3(288), dim3(256), 0, stream>>>(hend, prodE);
    k2_scanC<<<dim3(48 * 16), dim3(192), 0, stream>>>(dtsT, Bsw, Csw, u6T, A_logs, Ds, dtw, dtb, prodE, yssT);
    k3_out<<<dim3(256), dim3(256), 0, stream>>>(yssT, nw, nb, out);
}

// Round 8
// 190.235 us; speedup vs baseline: 2.5555x; 1.0966x over previous
//
#include <hip/hip_runtime.h>
#include <math.h>

typedef float f4 __attribute__((ext_vector_type(4)));
typedef float f2 __attribute__((ext_vector_type(2)));

#define L_LEN 2048
#define C_DIM 96
#define N_DIM 16
#define R_DIM 6
#define G_DIM 12
#define B_DIM 4
#define NCHUNK 64
#define CLEN 32
#define BGC (B_DIM * G_DIM * C_DIM) // 4608

// workspace layout (floats)
#define SZ_DTS (B_DIM * G_DIM * L_LEN * R_DIM)   // 589824
#define SZ_BC (B_DIM * G_DIM * N_DIM * L_LEN)    // 1572864
#define SZ_U6 (B_DIM * 6 * C_DIM * L_LEN)        // 4718592
#define SZ_Y (B_DIM * G_DIM * C_DIM * L_LEN)     // 9437184
#define SZ_H (BGC * NCHUNK * N_DIM)              // 4718592
#define SZ_X (B_DIM * 2 * C_DIM * 1024)          // 786432
#define SZ_WPAD (G_DIM * 40 * C_DIM)             // 46080

// ---------------- K0: transpose x (H<->W) for odd-k coalescing ----------------
__global__ __launch_bounds__(256) void k0_xT(
    const float* __restrict__ x, float* __restrict__ xT)
{
    __shared__ float t[32][33];
    int img = blockIdx.x; // (b,s,c) image, 768 total
    const float* src = x + (size_t)img * 1024;
    float* dst = xT + (size_t)img * 1024;
    int tx = threadIdx.x & 31, ty = threadIdx.x >> 5;
#pragma unroll
    for (int r = 0; r < 32; r += 8) t[ty + r][tx] = src[(ty + r) * 32 + tx];
    __syncthreads();
#pragma unroll
    for (int r = 0; r < 32; r += 8) dst[(ty + r) * 32 + tx] = t[tx][ty + r];
}

// ---------------- K0b: zero-pad x_proj_weight rows 38->40 ----------------
__global__ __launch_bounds__(256) void k0b_padw(
    const float* __restrict__ xpw, float* __restrict__ wpad)
{
    int i = blockIdx.x * 256 + (int)threadIdx.x; // < 46080
    if (i >= G_DIM * 40 * C_DIM) return;
    int g = i / (40 * C_DIM);
    int rem = i - g * 40 * C_DIM;
    int p = rem / C_DIM, c = rem - (rem / C_DIM) * C_DIM;
    wpad[i] = (p < 38) ? xpw[((size_t)g * 38 + p) * C_DIM + c] : 0.f;
}

// ---------------- K1: paired cross-scan gather + projections ----------------
__global__ __launch_bounds__(256) void k1_proj(
    const float* __restrict__ x, const float* __restrict__ xT,
    const float* __restrict__ wpad,
    float* __restrict__ dtsT, float* __restrict__ Bsw,
    float* __restrict__ Csw, float* __restrict__ u6T)
{
    __shared__ float Vsh[C_DIM * 68];
    __shared__ float Psh[40][68];

    int blk = blockIdx.x;      // bks*32 + ltile
    int ltile = blk & 31;
    int bks = blk >> 5;        // 0..23
    int s = bks % 3;
    int k = (bks / 3) & 1;
    int b = bks / 6;
    int g = k * 3 + s;         // 0..5
    int gh = g + 6;
    int l0 = ltile * 64;
    int l0h = (31 - ltile) * 64;
    int bg = b * G_DIM + g;
    int bgh = b * G_DIM + gh;
    int tid = (int)threadIdx.x;

    const float* xb = (k ? xT : x) + (size_t)b * 2 * C_DIM * 1024;

    // ---- stage V[c][ll] (f2 loads, f4 LDS writes) ----
#pragma unroll
    for (int j = 0; j < 6; ++j) {
        int e = tid + j * 256;       // < 1536
        int c = e >> 4;
        int llq = (e & 15) * 4;
        int pp = (l0 + llq) >> 1;
        f2 x0 = *(const f2*)(xb + (size_t)c * 1024 + pp);
        f2 x1 = *(const f2*)(xb + (size_t)(C_DIM + c) * 1024 + pp);
        f4 v;
        if (s == 2)      { v[0] = x0.x; v[1] = x1.x; v[2] = x0.y; v[3] = x1.y; }
        else if (s == 1) { v[0] = x1.x - x0.x; v[1] = x1.x; v[2] = x1.y - x0.y; v[3] = x1.y; }
        else             { v[0] = x0.x - x1.x; v[1] = x0.x; v[2] = x0.y - x1.y; v[3] = x0.y; }
        *(f4*)(Vsh + c * 68 + llq) = v;
    }
    __syncthreads();

    // ---- u6T[b6g][l][c] (coalesced f4, g<6 always here) ----
    {
        size_t ub = ((size_t)(b * 6 + g) * L_LEN + l0) * C_DIM;
#pragma unroll
        for (int j = 0; j < 6; ++j) {
            int e = tid + j * 256;
            int lidx = e / 24;
            int c4 = (e - lidx * 24) * 4;
            f4 v = { Vsh[(c4 + 0) * 68 + lidx], Vsh[(c4 + 1) * 68 + lidx],
                     Vsh[(c4 + 2) * 68 + lidx], Vsh[(c4 + 3) * 68 + lidx] };
            *(f4*)(u6T + ub + (size_t)lidx * C_DIM + c4) = v;
        }
    }

    // ---- register GEMM for g and gh (weights via scalar f4 loads) ----
    int ll = tid & 63;
    int P0 = __builtin_amdgcn_readfirstlane((tid >> 6) * 10);
    const float* wp = wpad + (size_t)g * 3840 + (size_t)P0 * C_DIM;
    const float* wph = wpad + (size_t)gh * 3840 + (size_t)P0 * C_DIM;

    float acc[10], acch[10];
#pragma unroll
    for (int p = 0; p < 10; ++p) { acc[p] = 0.f; acch[p] = 0.f; }

    for (int cb = 0; cb < C_DIM; cb += 8) {
        float vc[8], vch[8];
#pragma unroll
        for (int i = 0; i < 8; ++i) {
            vc[i] = Vsh[(cb + i) * 68 + ll];
            vch[i] = Vsh[(cb + i) * 68 + 63 - ll];
        }
#pragma unroll
        for (int p = 0; p < 10; ++p) {
#pragma unroll
            for (int q = 0; q < 2; ++q) {
                f4 w = *(const f4*)(wp + p * C_DIM + cb + q * 4);
                f4 wh = *(const f4*)(wph + p * C_DIM + cb + q * 4);
#pragma unroll
                for (int i = 0; i < 4; ++i) {
                    acc[p] = fmaf(w[i], vc[q * 4 + i], acc[p]);
                    acch[p] = fmaf(wh[i], vch[q * 4 + i], acch[p]);
                }
            }
        }
    }

    // ---- transpose via Psh, coalesced stores (g then gh) ----
#pragma unroll
    for (int gg = 0; gg < 2; ++gg) {
        __syncthreads();
#pragma unroll
        for (int p = 0; p < 10; ++p) Psh[P0 + p][ll] = gg ? acch[p] : acc[p];
        __syncthreads();
        int lb = gg ? l0h : l0;
        int bgx = gg ? bgh : bg;
        int q = tid & 3, lx = tid >> 2;
        f4 bv = { Psh[6 + q * 4 + 0][lx], Psh[6 + q * 4 + 1][lx],
                  Psh[6 + q * 4 + 2][lx], Psh[6 + q * 4 + 3][lx] };
        *(f4*)(Bsw + ((size_t)bgx * L_LEN + lb + lx) * N_DIM + q * 4) = bv;
        f4 cv = { Psh[22 + q * 4 + 0][lx], Psh[22 + q * 4 + 1][lx],
                  Psh[22 + q * 4 + 2][lx], Psh[22 + q * 4 + 3][lx] };
        *(f4*)(Csw + ((size_t)bgx * L_LEN + lb + lx) * N_DIM + q * 4) = cv;
        for (int e = tid; e < 64 * R_DIM; e += 256) {
            int lx2 = e / 6, r = e - (e / 6) * 6;
            dtsT[((size_t)bgx * L_LEN + lb + lx2) * R_DIM + r] = Psh[r][lx2];
        }
    }
}

// ---------------- K2: chunk-parallel scan, delta recomputed on the fly ----------------
__device__ __forceinline__ float softplus_f(float x)
{
    float sp = __logf(1.f + __expf(x));
    return (x > 60.f) ? x : sp;
}

// Pass A: per chunk with h0=0, compute h_end[16] and prodE[16]=exp2(a2*S).
__global__ __launch_bounds__(192) void k2_scanA(
    const float* __restrict__ dtsT, const float* __restrict__ Bsw,
    const float* __restrict__ u6T, const float* __restrict__ A_logs,
    const float* __restrict__ dtw, const float* __restrict__ dtb,
    float* __restrict__ hend, float* __restrict__ prodE)
{
    __shared__ f4 Bsh[256];     // 64 l x 16 n
    __shared__ float Dsh[384];  // 64 l x 6
    int blk = blockIdx.x;
    int chgrp = blk & 31;
    int bg = blk >> 5;
    int g = bg % G_DIM;
    int b = bg / G_DIM;
    int tid = (int)threadIdx.x;

    const f4* Bg = (const f4*)(Bsw + ((size_t)bg * L_LEN + chgrp * 64) * N_DIM);
    for (int i = tid; i < 256; i += 192) Bsh[i] = Bg[i];
    const float* Dg = dtsT + ((size_t)bg * L_LEN + chgrp * 64) * R_DIM;
    for (int i = tid; i < 384; i += 192) Dsh[i] = Dg[i];
    __syncthreads();

    int chl = tid / 96;
    int c = tid % 96;
    int ch = chgrp * 2 + chl;
    int bgc = bg * C_DIM + c;
    const bool rev = (g >= 6);
    int gu = rev ? (g - 6) : g;

    float a2[N_DIM];
    {
        const f4* Ap = (const f4*)(A_logs + ((size_t)g * C_DIM + c) * N_DIM);
        f4 Av[4] = { Ap[0], Ap[1], Ap[2], Ap[3] };
#pragma unroll
        for (int n = 0; n < N_DIM; ++n)
            a2[n] = -__expf(Av[n >> 2][n & 3]) * 1.44269504f;
    }
    float wdr[R_DIM];
    {
        const float* wdp = dtw + ((size_t)g * C_DIM + c) * R_DIM;
#pragma unroll
        for (int r = 0; r < R_DIM; ++r) wdr[r] = wdp[r];
    }
    float bias = dtb[g * C_DIM + c];

    const int LOFF = ch * CLEN;
    const float* up;
    int ustep;
    if (rev) { up = u6T + ((size_t)(b * 6 + gu) * L_LEN + (2047 - LOFF)) * C_DIM + c; ustep = -C_DIM; }
    else     { up = u6T + ((size_t)(b * 6 + gu) * L_LEN + LOFF) * C_DIM + c; ustep = C_DIM; }

    float h[N_DIM];
#pragma unroll
    for (int n = 0; n < N_DIM; ++n) h[n] = 0.f;
    float S = 0.f;

    float ubuf[4];
#pragma unroll
    for (int j = 0; j < 4; ++j) ubuf[j] = up[j * ustep];

    for (int jj = 0; jj < CLEN; jj += 4) {
        int nx = (jj + 4 < CLEN) ? jj + 4 : jj;
        float un[4];
#pragma unroll
        for (int j = 0; j < 4; ++j) un[j] = up[(nx + j) * ustep];
#pragma unroll
        for (int j = 0; j < 4; ++j) {
            int li = chl * CLEN + jj + j;
            float dt_ = bias;
#pragma unroll
            for (int r = 0; r < R_DIM; ++r) dt_ = fmaf(Dsh[li * R_DIM + r], wdr[r], dt_);
            float d = softplus_f(dt_);
            S += d;
            float du = d * ubuf[j];
            const f4* Bl = Bsh + (size_t)li * 4;
            f4 Bv[4] = { Bl[0], Bl[1], Bl[2], Bl[3] };
#pragma unroll
            for (int n = 0; n < N_DIM; ++n) {
                float e = exp2f(d * a2[n]);
                h[n] = fmaf(h[n], e, du * Bv[n >> 2][n & 3]);
            }
        }
#pragma unroll
        for (int j = 0; j < 4; ++j) ubuf[j] = un[j];
    }
    float* hp = hend + ((size_t)bgc * NCHUNK + ch) * N_DIM;
    float* pp = prodE + ((size_t)bgc * NCHUNK + ch) * N_DIM;
#pragma unroll
    for (int q = 0; q < 4; ++q) {
        f4 hv = { h[q * 4], h[q * 4 + 1], h[q * 4 + 2], h[q * 4 + 3] };
        f4 pv = { exp2f(a2[q * 4] * S), exp2f(a2[q * 4 + 1] * S),
                  exp2f(a2[q * 4 + 2] * S), exp2f(a2[q * 4 + 3] * S) };
        *(f4*)(hp + q * 4) = hv;
        *(f4*)(pp + q * 4) = pv;
    }
}

// Pass B: compose chunk propagators. Overwrites prodE with hstart (in place).
__global__ __launch_bounds__(256) void k2_fix(
    const float* __restrict__ hend, float* prodE_hstart)
{
    int t = blockIdx.x * 256 + (int)threadIdx.x; // 73728
    int n = t & 15;
    int bgc = t >> 4;
    float h = 0.f;
    for (int ch = 0; ch < NCHUNK; ++ch) {
        size_t idx = ((size_t)bgc * NCHUNK + ch) * N_DIM + n;
        float Pv = prodE_hstart[idx];
        float he = hend[idx];
        prodE_hstart[idx] = h;
        h = fmaf(h, Pv, he);
    }
}

// Pass C: exact recurrence from hstart, writes yT [bg][l][c] (+Ds*u folded).
__global__ __launch_bounds__(192) void k2_scanC(
    const float* __restrict__ dtsT, const float* __restrict__ Bsw,
    const float* __restrict__ Csw, const float* __restrict__ u6T,
    const float* __restrict__ A_logs, const float* __restrict__ Ds,
    const float* __restrict__ dtw, const float* __restrict__ dtb,
    const float* __restrict__ hstart, float* __restrict__ yssT)
{
    __shared__ f4 Bsh[256];
    __shared__ f4 Csh[256];
    __shared__ float Dsh[384];
    int blk = blockIdx.x;
    int chgrp = blk & 31;
    int bg = blk >> 5;
    int g = bg % G_DIM;
    int b = bg / G_DIM;
    int tid = (int)threadIdx.x;

    const f4* Bg = (const f4*)(Bsw + ((size_t)bg * L_LEN + chgrp * 64) * N_DIM);
    const f4* Cg = (const f4*)(Csw + ((size_t)bg * L_LEN + chgrp * 64) * N_DIM);
    for (int i = tid; i < 256; i += 192) { Bsh[i] = Bg[i]; Csh[i] = Cg[i]; }
    const float* Dg = dtsT + ((size_t)bg * L_LEN + chgrp * 64) * R_DIM;
    for (int i = tid; i < 384; i += 192) Dsh[i] = Dg[i];
    __syncthreads();

    int chl = tid / 96;
    int c = tid % 96;
    int ch = chgrp * 2 + chl;
    int bgc = bg * C_DIM + c;
    const bool rev = (g >= 6);
    int gu = rev ? (g - 6) : g;

    float a2[N_DIM];
    {
        const f4* Ap = (const f4*)(A_logs + ((size_t)g * C_DIM + c) * N_DIM);
        f4 Av[4] = { Ap[0], Ap[1], Ap[2], Ap[3] };
#pragma unroll
        for (int n = 0; n < N_DIM; ++n)
            a2[n] = -__expf(Av[n >> 2][n & 3]) * 1.44269504f;
    }
    float wdr[R_DIM];
    {
        const float* wdp = dtw + ((size_t)g * C_DIM + c) * R_DIM;
#pragma unroll
        for (int r = 0; r < R_DIM; ++r) wdr[r] = wdp[r];
    }
    float bias = dtb[g * C_DIM + c];
    float dsc = Ds[g * C_DIM + c];

    const int LOFF = ch * CLEN;
    const float* up;
    int ustep;
    if (rev) { up = u6T + ((size_t)(b * 6 + gu) * L_LEN + (2047 - LOFF)) * C_DIM + c; ustep = -C_DIM; }
    else     { up = u6T + ((size_t)(b * 6 + gu) * L_LEN + LOFF) * C_DIM + c; ustep = C_DIM; }
    float* yp = yssT + ((size_t)bg * L_LEN + LOFF) * C_DIM + c;

    float h[N_DIM];
    {
        const f4* Hp = (const f4*)(hstart + ((size_t)bgc * NCHUNK + ch) * N_DIM);
        f4 Hv[4] = { Hp[0], Hp[1], Hp[2], Hp[3] };
#pragma unroll
        for (int n = 0; n < N_DIM; ++n) h[n] = Hv[n >> 2][n & 3];
    }

    float ubuf[4];
#pragma unroll
    for (int j = 0; j < 4; ++j) ubuf[j] = up[j * ustep];

    for (int jj = 0; jj < CLEN; jj += 4) {
        int nx = (jj + 4 < CLEN) ? jj + 4 : jj;
        float un[4];
#pragma unroll
        for (int j = 0; j < 4; ++j) un[j] = up[(nx + j) * ustep];
#pragma unroll
        for (int j = 0; j < 4; ++j) {
            int li = chl * CLEN + jj + j;
            float dt_ = bias;
#pragma unroll
            for (int r = 0; r < R_DIM; ++r) dt_ = fmaf(Dsh[li * R_DIM + r], wdr[r], dt_);
            float d = softplus_f(dt_);
            float uu = ubuf[j];
            float du = d * uu;
            const f4* Bl = Bsh + (size_t)li * 4;
            const f4* Cl = Csh + (size_t)li * 4;
            f4 Bv[4] = { Bl[0], Bl[1], Bl[2], Bl[3] };
            f4 Cv[4] = { Cl[0], Cl[1], Cl[2], Cl[3] };
            float y = dsc * uu;
#pragma unroll
            for (int n = 0; n < N_DIM; ++n) {
                float e = exp2f(d * a2[n]);
                h[n] = fmaf(h[n], e, du * Bv[n >> 2][n & 3]);
                y = fmaf(h[n], Cv[n >> 2][n & 3], y);
            }
            yp[(jj + j) * C_DIM] = y;
        }
#pragma unroll
        for (int j = 0; j < 4; ++j) ubuf[j] = un[j];
    }
}

// ---------------- K3: fold (un-scan) + LayerNorm, fused ([l][c] input) ----------------
__global__ __launch_bounds__(256) void k3_out(
    const float* __restrict__ yssT, const float* __restrict__ nw,
    const float* __restrict__ nb, float* __restrict__ out)
{
    __shared__ float tA[32][97];
    __shared__ float tB[32][97];
    __shared__ float ps[4][8][32];
    __shared__ float stat[4][32];

    int blk = blockIdx.x;
    int h = blk & 31;
    int bs = blk >> 5;
    int so = bs & 1;
    int b = bs >> 1;
    int tid = (int)threadIdx.x;

    auto Y = [&](int g) { return yssT + (size_t)(b * 12 + g) * L_LEN * C_DIM; };
    const float* Y0 = Y(so);
    const float* Y0r = Y(6 + so);
    const float* Y1 = Y(3 + so);
    const float* Y1r = Y(9 + so);

#pragma unroll 2
    for (int it = 0; it < 24; ++it) {
        int idx = tid + it * 256;
        int c = idx % 96, rest = idx / 96;
        int w = rest >> 1, par = rest & 1;
        int a0 = h * 64 + rest;
        int a1 = w * 64 + 2 * h + par;
        float v = Y0[(size_t)a0 * C_DIM + c] + Y0r[(size_t)(2047 - a0) * C_DIM + c]
                + Y1[(size_t)a1 * C_DIM + c] + Y1r[(size_t)(2047 - a1) * C_DIM + c];
        if (par) tA[w][c] = v; else tB[w][c] = v;
    }
    __syncthreads();

    int w = tid & 31, cg = tid >> 5;
    float sA = 0, qA = 0, sB = 0, qB = 0;
#pragma unroll
    for (int j = 0; j < 12; ++j) {
        float yv = tA[w][cg * 12 + j], dv = tB[w][cg * 12 + j];
        sA += yv; qA += yv * yv; sB += dv; qB += dv * dv;
    }
    ps[0][cg][w] = sA; ps[1][cg][w] = qA; ps[2][cg][w] = sB; ps[3][cg][w] = qB;
    __syncthreads();
    if (tid < 32) {
        int ww = tid;
        float t0 = 0, t1 = 0, t2 = 0, t3 = 0;
#pragma unroll
        for (int q = 0; q < 8; ++q) {
            t0 += ps[0][q][ww]; t1 += ps[1][q][ww];
            t2 += ps[2][q][ww]; t3 += ps[3][q][ww];
        }
        float muA = t0 * (1.f / 96.f), eqA = t1 * (1.f / 96.f);
        float muB = t2 * (1.f / 96.f), eqB = t3 * (1.f / 96.f);
        stat[0][ww] = muA; stat[1][ww] = rsqrtf(eqA - muA * muA + 1e-5f);
        stat[2][ww] = muB; stat[3][ww] = rsqrtf(eqB - muB * muB + 1e-5f);
    }
    __syncthreads();
    size_t obase = (size_t)blk * 3072;
    for (int e = tid; e < 3072; e += 256) {
        int ww = e / 96, c = e % 96;
        float wc = nw[c], bc = nb[c];
        out[obase + e] = (tA[ww][c] - stat[0][ww]) * stat[1][ww] * wc + bc;
        out[2 * 786432 + obase + e] = (tB[ww][c] - stat[2][ww]) * stat[3][ww] * wc + bc;
    }
    __syncthreads();

    const float* Y2 = Y(2);
    const float* Y2r = Y(8);
    const float* Y3 = Y(5);
    const float* Y3r = Y(11);
#pragma unroll 2
    for (int it = 0; it < 12; ++it) {
        int idx = tid + it * 256;
        int c = idx % 96, w2 = idx / 96;
        int a0 = h * 64 + 2 * w2 + so;
        int a1 = w2 * 64 + 2 * h + so;
        float v = Y2[(size_t)a0 * C_DIM + c] + Y2r[(size_t)(2047 - a0) * C_DIM + c]
                + Y3[(size_t)a1 * C_DIM + c] + Y3r[(size_t)(2047 - a1) * C_DIM + c];
        tA[w2][c] = v;
    }
    __syncthreads();
    float sC = 0, qC = 0;
#pragma unroll
    for (int j = 0; j < 12; ++j) {
        float v = tA[w][cg * 12 + j];
        sC += v; qC += v * v;
    }
    ps[0][cg][w] = sC; ps[1][cg][w] = qC;
    __syncthreads();
    if (tid < 32) {
        int ww = tid;
        float t0 = 0, t1 = 0;
#pragma unroll
        for (int q = 0; q < 8; ++q) { t0 += ps[0][q][ww]; t1 += ps[1][q][ww]; }
        float mu = t0 * (1.f / 96.f), eq = t1 * (1.f / 96.f);
        stat[0][ww] = mu; stat[1][ww] = rsqrtf(eq - mu * mu + 1e-5f);
    }
    __syncthreads();
    for (int e = tid; e < 3072; e += 256) {
        int ww = e / 96, c = e % 96;
        out[786432 + obase + e] = (tA[ww][c] - stat[0][ww]) * stat[1][ww] * nw[c] + nb[c];
    }
}

extern "C" void kernel_launch(void* const* d_in, const int* in_sizes, int n_in,
                              void* d_out, int out_size, void* d_ws, size_t ws_size,
                              hipStream_t stream)
{
    const float* x = (const float*)d_in[0];
    const float* xpw = (const float*)d_in[1];
    const float* dtw = (const float*)d_in[2];
    const float* dtb = (const float*)d_in[3];
    const float* A_logs = (const float*)d_in[4];
    const float* Ds = (const float*)d_in[5];
    const float* nw = (const float*)d_in[6];
    const float* nb = (const float*)d_in[7];
    float* out = (float*)d_out;

    float* ws = (float*)d_ws;
    float* dtsT = ws;                  // SZ_DTS
    float* Bsw = dtsT + SZ_DTS;        // SZ_BC
    float* Csw = Bsw + SZ_BC;          // SZ_BC
    float* u6T = Csw + SZ_BC;          // SZ_U6
    float* yssT = u6T + SZ_U6;         // SZ_Y
    float* hend = yssT + SZ_Y;         // SZ_H
    float* prodE = hend + SZ_H;        // SZ_H (then reused as hstart)
    float* xT = prodE + SZ_H;          // SZ_X
    float* wpad = xT + SZ_X;           // SZ_WPAD

    k0_xT<<<dim3(768), dim3(256), 0, stream>>>(x, xT);
    k0b_padw<<<dim3(180), dim3(256), 0, stream>>>(xpw, wpad);
    k1_proj<<<dim3(24 * 32), dim3(256), 0, stream>>>(x, xT, wpad, dtsT, Bsw, Csw, u6T);
    k2_scanA<<<dim3(48 * 32), dim3(192), 0, stream>>>(dtsT, Bsw, u6T, A_logs, dtw, dtb, hend, prodE);
    k2_fix<<<dim3(288), dim3(256), 0, stream>>>(hend, prodE);
    k2_scanC<<<dim3(48 * 32), dim3(192), 0, stream>>>(dtsT, Bsw, Csw, u6T, A_logs, Ds, dtw, dtb, prodE, yssT);
    k3_out<<<dim3(256), dim3(256), 0, stream>>>(yssT, nw, nb, out);
}